// Round 14
// baseline (1252.979 us; speedup 1.0000x reference)
//
#include <hip/hip_runtime.h>
#include <hip/hip_bf16.h>

#define T2 2048
#define H2 256
#define BT2 131072          // B*T = 64*2048
#define MAXP 4

typedef __attribute__((ext_vector_type(8))) short bf16x8;
typedef __attribute__((ext_vector_type(4))) float f32x4;
typedef unsigned short u16;

__device__ __forceinline__ u16 f2bf(float f) {
    union { float f; unsigned u; } v; v.f = f;
    unsigned r = (v.u + 0x7FFFu + ((v.u >> 16) & 1u)) >> 16;
    return (u16)r;
}
__device__ __forceinline__ void async16(const void* g, void* l) {
    __builtin_amdgcn_global_load_lds((const __attribute__((address_space(1))) void*)g,
                                     (__attribute__((address_space(3))) void*)l, 16, 0, 0);
}
__device__ __forceinline__ float frcp(float x) { return __builtin_amdgcn_rcpf(x); }
__device__ __forceinline__ float sig_f(float x) { return frcp(1.f + __expf(-x)); }
__device__ __forceinline__ float tanh_f(float x) {
    return 1.f - 2.f * frcp(__expf(2.f * x) + 1.f);
}

// f32 -> bf16 cast, 4 elems/thread (adjacency only)
__global__ __launch_bounds__(256) void cast_bf16_k(
    const float* __restrict__ in, u16* __restrict__ out, int n4)
{
    const int i = blockIdx.x * 256 + threadIdx.x;
    if (i >= n4) return;
    const float4 v = ((const float4*)in)[i];
    ushort4 h;
    h.x = f2bf(v.x); h.y = f2bf(v.y); h.z = f2bf(v.z); h.w = f2bf(v.w);
    ((ushort4*)out)[i] = h;
}

// ---------------------------------------------------------------------------
// Support GEMM 1, fused f32-A (__syncthreads kept: ds_write staging needs
// the lgkm drain): C^T = (x_f32 @ Bt^T + bias) -> bf16 St.
// ---------------------------------------------------------------------------
__global__ __launch_bounds__(256) void bgemm_sup_f32a_k(
    const float* __restrict__ A, const u16* __restrict__ Bt,
    const float* __restrict__ bias, u16* __restrict__ Ct)
{
    __shared__ __align__(16) u16 As[2][128][64];
    __shared__ __align__(16) u16 Bs[2][128][64];
    const int K = 256;

    const int tid = threadIdx.x;
    const int wid = tid >> 6, lane = tid & 63;
    const int wr = wid >> 1, wc = wid & 1;
    const int bx = blockIdx.x >> 1, by = blockIdx.x & 1;
    const int row0 = bx * 128, col0 = by * 128;

    const int srow = tid >> 3;
    const int skA = ((tid ^ srow) & 7) << 3;
    const float* Agf = A + (size_t)(row0 + srow) * K + skA;
    const u16* Bg = Bt + (size_t)(col0 + srow) * K + skA;
    char* ldsA = (char*)&As[0][0][0];
    char* ldsB = (char*)&Bs[0][0][0];
    const int wb = wid << 10;
    const int awr = srow * 128 + (tid & 7) * 16;

    f32x4 acc[4][4];
    #pragma unroll
    for (int i = 0; i < 4; ++i)
        #pragma unroll
        for (int q = 0; q < 4; ++q) acc[i][q] = (f32x4){0.f, 0.f, 0.f, 0.f};

    #pragma unroll
    for (int s = 0; s < 4; ++s) {
        const float4 u0 = *(const float4*)(Agf + (size_t)(s * 32) * K);
        const float4 u1 = *(const float4*)(Agf + (size_t)(s * 32) * K + 4);
        ushort4 h0, h1;
        h0.x = f2bf(u0.x); h0.y = f2bf(u0.y); h0.z = f2bf(u0.z); h0.w = f2bf(u0.w);
        h1.x = f2bf(u1.x); h1.y = f2bf(u1.y); h1.z = f2bf(u1.z); h1.w = f2bf(u1.w);
        *(ushort4*)(ldsA + s * 4096 + awr) = h0;
        *(ushort4*)(ldsA + s * 4096 + awr + 8) = h1;
        async16(Bg + (size_t)(s * 32) * K, ldsB + s * 4096 + wb);
    }
    __syncthreads();

    int cur = 0;
    for (int k0 = 0; k0 < K; k0 += 64) {
        if (k0 + 64 < K) {
            char* dA = ldsA + ((cur ^ 1) << 14);
            char* dB = ldsB + ((cur ^ 1) << 14);
            #pragma unroll
            for (int s = 0; s < 4; ++s) {
                const float4 u0 = *(const float4*)(Agf + (size_t)(s * 32) * K + k0 + 64);
                const float4 u1 = *(const float4*)(Agf + (size_t)(s * 32) * K + k0 + 68);
                ushort4 h0, h1;
                h0.x = f2bf(u0.x); h0.y = f2bf(u0.y); h0.z = f2bf(u0.z); h0.w = f2bf(u0.w);
                h1.x = f2bf(u1.x); h1.y = f2bf(u1.y); h1.z = f2bf(u1.z); h1.w = f2bf(u1.w);
                *(ushort4*)(dA + s * 4096 + awr) = h0;
                *(ushort4*)(dA + s * 4096 + awr + 8) = h1;
                async16(Bg + (size_t)(s * 32) * K + k0 + 64, dB + s * 4096 + wb);
            }
        }
        char* rA = ldsA + (cur << 14);
        char* rB = ldsB + (cur << 14);
        const int mb = lane & 15, g = lane >> 4;
        #pragma unroll
        for (int kk = 0; kk < 2; ++kk) {
            bf16x8 a[4], b[4];
            #pragma unroll
            for (int i = 0; i < 4; ++i) {
                const int r = wr * 64 + i * 16 + mb;
                a[i] = *(const bf16x8*)(rA + r * 128 + ((((kk << 2) + g) ^ (r & 7)) << 4));
            }
            #pragma unroll
            for (int q = 0; q < 4; ++q) {
                const int r = wc * 64 + q * 16 + mb;
                b[q] = *(const bf16x8*)(rB + r * 128 + ((((kk << 2) + g) ^ (r & 7)) << 4));
            }
            #pragma unroll
            for (int i = 0; i < 4; ++i)
                #pragma unroll
                for (int q = 0; q < 4; ++q)
                    acc[i][q] = __builtin_amdgcn_mfma_f32_16x16x32_bf16(a[i], b[q], acc[i][q], 0, 0, 0);
        }
        __syncthreads();
        cur ^= 1;
    }

    #pragma unroll
    for (int i = 0; i < 4; ++i) {
        const int grow = row0 + wr * 64 + i * 16 + ((lane >> 4) << 2);
        #pragma unroll
        for (int q = 0; q < 4; ++q) {
            const int col = col0 + wc * 64 + q * 16 + (lane & 15);
            f32x4 v = acc[i][q];
            const float bv = bias[col];
            ushort4 pk;
            pk.x = f2bf(v[0] + bv); pk.y = f2bf(v[1] + bv);
            pk.z = f2bf(v[2] + bv); pk.w = f2bf(v[3] + bv);
            *(ushort4*)(Ct + ((size_t)((grow >> 11) * 256 + col)) * 2048 + (grow & 2047)) = pk;
        }
    }
}

// ---------------------------------------------------------------------------
// Support GEMM (bf16 A), counted-vmcnt pipeline: C^T = (A @ Bt^T + bias) -> St.
// ---------------------------------------------------------------------------
__global__ __launch_bounds__(256) void bgemm_sup_k(
    const u16* __restrict__ A, const u16* __restrict__ Bt,
    const float* __restrict__ bias, u16* __restrict__ Ct)
{
    __shared__ __align__(16) u16 As[2][128][64];
    __shared__ __align__(16) u16 Bs[2][128][64];
    const int K = 256;

    const int tid = threadIdx.x;
    const int wid = tid >> 6, lane = tid & 63;
    const int wr = wid >> 1, wc = wid & 1;
    const int bx = blockIdx.x >> 1, by = blockIdx.x & 1;
    const int row0 = bx * 128, col0 = by * 128;

    const int srow = tid >> 3;
    const int skA = ((tid ^ srow) & 7) << 3;
    const u16* Ag = A + (size_t)(row0 + srow) * K + skA;
    const u16* Bg = Bt + (size_t)(col0 + srow) * K + skA;
    char* ldsA = (char*)&As[0][0][0];
    char* ldsB = (char*)&Bs[0][0][0];
    const int wb = wid << 10;

    f32x4 acc[4][4];
    #pragma unroll
    for (int i = 0; i < 4; ++i)
        #pragma unroll
        for (int q = 0; q < 4; ++q) acc[i][q] = (f32x4){0.f, 0.f, 0.f, 0.f};

    #pragma unroll
    for (int s = 0; s < 4; ++s) {
        async16(Ag + (size_t)(s * 32) * K, ldsA + s * 4096 + wb);
        async16(Bg + (size_t)(s * 32) * K, ldsB + s * 4096 + wb);
    }

    int cur = 0;
    for (int k0 = 0; k0 < K; k0 += 64) {
        if (k0 + 64 < K) {
            char* dA = ldsA + ((cur ^ 1) << 14);
            char* dB = ldsB + ((cur ^ 1) << 14);
            #pragma unroll
            for (int s = 0; s < 4; ++s) {
                async16(Ag + (size_t)(s * 32) * K + k0 + 64, dA + s * 4096 + wb);
                async16(Bg + (size_t)(s * 32) * K + k0 + 64, dB + s * 4096 + wb);
            }
            asm volatile("s_waitcnt vmcnt(8)" ::: "memory");
        } else {
            asm volatile("s_waitcnt vmcnt(0)" ::: "memory");
        }
        __builtin_amdgcn_s_barrier();
        __builtin_amdgcn_sched_barrier(0);
        char* rA = ldsA + (cur << 14);
        char* rB = ldsB + (cur << 14);
        const int mb = lane & 15, g = lane >> 4;
        #pragma unroll
        for (int kk = 0; kk < 2; ++kk) {
            bf16x8 a[4], b[4];
            #pragma unroll
            for (int i = 0; i < 4; ++i) {
                const int r = wr * 64 + i * 16 + mb;
                a[i] = *(const bf16x8*)(rA + r * 128 + ((((kk << 2) + g) ^ (r & 7)) << 4));
            }
            #pragma unroll
            for (int q = 0; q < 4; ++q) {
                const int r = wc * 64 + q * 16 + mb;
                b[q] = *(const bf16x8*)(rB + r * 128 + ((((kk << 2) + g) ^ (r & 7)) << 4));
            }
            #pragma unroll
            for (int i = 0; i < 4; ++i)
                #pragma unroll
                for (int q = 0; q < 4; ++q)
                    acc[i][q] = __builtin_amdgcn_mfma_f32_16x16x32_bf16(a[i], b[q], acc[i][q], 0, 0, 0);
        }
        __builtin_amdgcn_s_barrier();
        cur ^= 1;
    }

    #pragma unroll
    for (int i = 0; i < 4; ++i) {
        const int grow = row0 + wr * 64 + i * 16 + ((lane >> 4) << 2);
        #pragma unroll
        for (int q = 0; q < 4; ++q) {
            const int col = col0 + wc * 64 + q * 16 + (lane & 15);
            f32x4 v = acc[i][q];
            const float bv = bias[col];
            ushort4 pk;
            pk.x = f2bf(v[0] + bv); pk.y = f2bf(v[1] + bv);
            pk.z = f2bf(v[2] + bv); pk.w = f2bf(v[3] + bv);
            *(ushort4*)(Ct + ((size_t)((grow >> 11) * 256 + col)) * 2048 + (grow & 2047)) = pk;
        }
    }
}

// ---------------------------------------------------------------------------
// Adjacency GEMM: counted-vmcnt pipeline + supertile XCD decode.
// ---------------------------------------------------------------------------
__global__ __launch_bounds__(256) void bgemm_adj_k(
    const u16* __restrict__ A, const u16* __restrict__ Bt,
    u16* __restrict__ Cx, int K, long long bsB)
{
    __shared__ __align__(16) u16 As[2][128][64];
    __shared__ __align__(16) u16 Bs[2][128][64];

    const int tid = threadIdx.x;
    const int wid = tid >> 6, lane = tid & 63;
    const int wr = wid >> 1, wc = wid & 1;

    const int xcd = blockIdx.x & 7, loc = blockIdx.x >> 3;
    const int s = loc >> 4, w = loc & 15;
    const int sg = xcd * 16 + s;
    const int pzg = sg >> 2, bxg = sg & 3;
    const int bx = bxg * 4 + (w >> 2);
    const int pzidx = pzg * 4 + (w & 3);
    const int by = pzidx >> 6, bz = pzidx & 63;

    const int row0 = bx * 128, col0 = by * 128;
    const u16* Bp = Bt + (long long)bz * bsB;

    const int srow = tid >> 3;
    const int skA = ((tid ^ srow) & 7) << 3;
    const u16* Ag = A + (size_t)(row0 + srow) * K + skA;
    const u16* Bg = Bp + (size_t)(col0 + srow) * K + skA;
    char* ldsA = (char*)&As[0][0][0];
    char* ldsB = (char*)&Bs[0][0][0];
    const int wb = wid << 10;

    f32x4 acc[4][4];
    #pragma unroll
    for (int i = 0; i < 4; ++i)
        #pragma unroll
        for (int q = 0; q < 4; ++q) acc[i][q] = (f32x4){0.f, 0.f, 0.f, 0.f};

    #pragma unroll
    for (int s2 = 0; s2 < 4; ++s2) {
        async16(Ag + (size_t)(s2 * 32) * K, ldsA + s2 * 4096 + wb);
        async16(Bg + (size_t)(s2 * 32) * K, ldsB + s2 * 4096 + wb);
    }

    int cur = 0;
    for (int k0 = 0; k0 < K; k0 += 64) {
        if (k0 + 64 < K) {
            char* dA = ldsA + ((cur ^ 1) << 14);
            char* dB = ldsB + ((cur ^ 1) << 14);
            #pragma unroll
            for (int s2 = 0; s2 < 4; ++s2) {
                async16(Ag + (size_t)(s2 * 32) * K + k0 + 64, dA + s2 * 4096 + wb);
                async16(Bg + (size_t)(s2 * 32) * K + k0 + 64, dB + s2 * 4096 + wb);
            }
            asm volatile("s_waitcnt vmcnt(8)" ::: "memory");
        } else {
            asm volatile("s_waitcnt vmcnt(0)" ::: "memory");
        }
        __builtin_amdgcn_s_barrier();
        __builtin_amdgcn_sched_barrier(0);
        char* rA = ldsA + (cur << 14);
        char* rB = ldsB + (cur << 14);
        const int mb = lane & 15, g = lane >> 4;
        #pragma unroll
        for (int kk = 0; kk < 2; ++kk) {
            bf16x8 a[4], b[4];
            #pragma unroll
            for (int i = 0; i < 4; ++i) {
                const int r = wr * 64 + i * 16 + mb;
                a[i] = *(const bf16x8*)(rA + r * 128 + ((((kk << 2) + g) ^ (r & 7)) << 4));
            }
            #pragma unroll
            for (int q = 0; q < 4; ++q) {
                const int r = wc * 64 + q * 16 + mb;
                b[q] = *(const bf16x8*)(rB + r * 128 + ((((kk << 2) + g) ^ (r & 7)) << 4));
            }
            #pragma unroll
            for (int i = 0; i < 4; ++i)
                #pragma unroll
                for (int q = 0; q < 4; ++q)
                    acc[i][q] = __builtin_amdgcn_mfma_f32_16x16x32_bf16(a[i], b[q], acc[i][q], 0, 0, 0);
        }
        __builtin_amdgcn_s_barrier();
        cur ^= 1;
    }

    #pragma unroll
    for (int i = 0; i < 4; ++i) {
        const int grow = row0 + wr * 64 + i * 16 + ((lane >> 4) << 2);
        #pragma unroll
        for (int q = 0; q < 4; ++q) {
            const int col = col0 + wc * 64 + q * 16 + (lane & 15);
            f32x4 v = acc[i][q];
            #pragma unroll
            for (int r = 0; r < 4; ++r)
                Cx[((size_t)bz * 2048 + grow + r) * 256 + col] = f2bf(fmaxf(v[r], 0.f));
        }
    }
}

// is output position tt overwritten by a later pass?
__device__ __forceinline__ bool keep_out(int p, int tt) {
    if (p == 1) return ((tt & 1) == 0) && (tt % 3 != 2) && ((tt & 3) != 3);
    if (p == 2) return (tt % 3 != 2) && ((tt & 3) != 3);
    if (p == 3) return ((tt & 3) != 3);
    return true;
}

// decompose n -> (batch b, window w): shift path for pow2 nw (p=1,2,4)
__device__ __forceinline__ void bw_of(int n, int nw, int nwSh, unsigned& b, int& w) {
    if (nwSh >= 0) { b = (unsigned)n >> nwSh; w = n & (nw - 1); }
    else { b = (unsigned)n / (unsigned)nw; w = n - (int)b * nw; }
}

// ---------------------------------------------------------------------------
// LSTM step, M=128 tile, counted-vmcnt pipeline (8 loads/step), 64KB LDS ->
// 2 blocks/CU. Epilogue uses shift-based (b,w) decompose for pow2 nw.
// ---------------------------------------------------------------------------
__global__ __launch_bounds__(256) void lstm_step_k(
    const u16* __restrict__ xsrc, const u16* __restrict__ hprev,
    u16* __restrict__ hnext, float* __restrict__ outF, float* __restrict__ cst,
    const u16* __restrict__ wih, const u16* __restrict__ whh,
    const float* __restrict__ biasp, int nw, int nwSh, int p, int j, int cpx, int writeH)
{
    __shared__ __align__(16) u16 As[2][128][64];
    __shared__ __align__(16) u16 Bs[2][128][64];

    const int tid = threadIdx.x;
    const int wid = tid >> 6, lane = tid & 63;
    const int wr = wid >> 1, wc = wid & 1;

    const int l = (blockIdx.x & 7) * cpx + (blockIdx.x >> 3);
    const int col0 = (l & 7) << 7;
    const int row0 = (l >> 3) << 7;
    const int first = (j == 0), last = (j == p - 1);

    const int srow = tid >> 3;
    const int skA = ((tid ^ srow) & 7) << 3;

    const u16* axp[4];
    const u16* hpp[4];
    size_t wrow[4];
    #pragma unroll
    for (int s = 0; s < 4; ++s) {
        const int r = srow + 32 * s;
        const int n = row0 + r;
        unsigned b; int w;
        bw_of(n, nw, nwSh, b, w);
        axp[s] = xsrc + ((size_t)b * T2 + (size_t)w * p + j) * H2 + skA;
        hpp[s] = hprev ? hprev + (size_t)n * H2 + skA : nullptr;
        wrow[s] = (size_t)(col0 + r) * H2 + skA;
    }
    char* ldsA = (char*)&As[0][0][0];
    char* ldsB = (char*)&Bs[0][0][0];
    const int wb = wid << 10;

    f32x4 acc[4][4];
    #pragma unroll
    for (int i = 0; i < 4; ++i)
        #pragma unroll
        for (int q = 0; q < 4; ++q) acc[i][q] = (f32x4){0.f, 0.f, 0.f, 0.f};

    const int KT = first ? 256 : 512;

    // prologue: stage tile 0 (x-part) into buf 0 -- 8 loads/wave
    #pragma unroll
    for (int s = 0; s < 4; ++s) {
        async16(axp[s], ldsA + s * 4096 + wb);
        async16(wih + wrow[s], ldsB + s * 4096 + wb);
    }

    int cur = 0;
    for (int k0 = 0; k0 < KT; k0 += 64) {
        const int kn = k0 + 64;
        if (kn < KT) {
            char* dA = ldsA + ((cur ^ 1) << 14);
            char* dB = ldsB + ((cur ^ 1) << 14);
            if (kn < 256) {
                #pragma unroll
                for (int s = 0; s < 4; ++s) {
                    async16(axp[s] + kn, dA + s * 4096 + wb);
                    async16(wih + wrow[s] + kn, dB + s * 4096 + wb);
                }
            } else {
                const int kk2 = kn - 256;
                #pragma unroll
                for (int s = 0; s < 4; ++s) {
                    async16(hpp[s] + kk2, dA + s * 4096 + wb);
                    async16(whh + wrow[s] + kk2, dB + s * 4096 + wb);
                }
            }
            asm volatile("s_waitcnt vmcnt(8)" ::: "memory");
        } else {
            asm volatile("s_waitcnt vmcnt(0)" ::: "memory");
        }
        __builtin_amdgcn_s_barrier();
        __builtin_amdgcn_sched_barrier(0);
        char* rA = ldsA + (cur << 14);
        char* rB = ldsB + (cur << 14);
        const int mb = lane & 15, g = lane >> 4;
        #pragma unroll
        for (int kk = 0; kk < 2; ++kk) {
            bf16x8 a[4], b[4];
            #pragma unroll
            for (int i = 0; i < 4; ++i) {
                const int r = wr * 64 + i * 16 + mb;
                a[i] = *(const bf16x8*)(rA + r * 128 + ((((kk << 2) + g) ^ (r & 7)) << 4));
            }
            #pragma unroll
            for (int q = 0; q < 4; ++q) {
                const int r = wc * 64 + q * 16 + mb;
                b[q] = *(const bf16x8*)(rB + r * 128 + ((((kk << 2) + g) ^ (r & 7)) << 4));
            }
            #pragma unroll
            for (int i = 0; i < 4; ++i)
                #pragma unroll
                for (int q = 0; q < 4; ++q)
                    acc[i][q] = __builtin_amdgcn_mfma_f32_16x16x32_bf16(a[i], b[q], acc[i][q], 0, 0, 0);
        }
        __builtin_amdgcn_s_barrier();
        cur ^= 1;
    }

    const int u = lane & 15;
    const int colb = col0 + wc * 64;
    const int hu = (colb >> 2) + u;
    float bq[4];
    #pragma unroll
    for (int q = 0; q < 4; ++q) bq[q] = biasp[colb + q * 16 + u];

    #pragma unroll
    for (int i = 0; i < 4; ++i) {
        const int rbase = row0 + wr * 64 + i * 16 + ((lane >> 4) << 2);
        #pragma unroll
        for (int r = 0; r < 4; ++r) {
            const int n = rbase + r;
            const float gi = acc[i][0][r] + bq[0];
            const float gf = acc[i][1][r] + bq[1];
            const float gg = acc[i][2][r] + bq[2];
            const float go = acc[i][3][r] + bq[3];
            const float si = sig_f(gi), sf = sig_f(gf), so = sig_f(go);
            const float tg = tanh_f(gg);
            const float cp = first ? 0.f : cst[(size_t)n * H2 + hu];
            const float cn = sf * cp + si * tg;
            const float hv = so * tanh_f(cn);
            if (writeH) hnext[(size_t)n * H2 + hu] = f2bf(hv);
            if (last) {
                unsigned b; int w;
                bw_of(n, nw, nwSh, b, w);
                const int tt = w * p + (p - 1);
                if (keep_out(p, tt))
                    outF[((size_t)b * T2 + tt) * H2 + hu] = hv;
            } else {
                cst[(size_t)n * H2 + hu] = cn;
            }
        }
    }
}

// update mirror at window-end positions from deferred hnext (bf16 copy)
__global__ __launch_bounds__(256) void scatter_ax_k(
    const u16* __restrict__ hs, u16* __restrict__ mir, int nw, int nwSh, int p, int Nrows)
{
    const int idx = blockIdx.x * 256 + threadIdx.x;
    if (idx >= Nrows * 32) return;
    const int n = idx >> 5, c8 = (idx & 31) << 3;
    unsigned b; int w;
    bw_of(n, nw, nwSh, b, w);
    *(uint4*)(mir + ((size_t)b * T2 + (size_t)w * p + (p - 1)) * H2 + c8) =
        *(const uint4*)(hs + (size_t)n * H2 + c8);
}

// Wg transpose+cast: out[n][k] = bf16(in[k][n]), 256x256
__global__ __launch_bounds__(256) void convT_k(const float* __restrict__ in, u16* __restrict__ out)
{
    const int idx = blockIdx.x * 256 + threadIdx.x;
    const int r = idx >> 8, c = idx & 255;
    out[(size_t)c * 256 + r] = f2bf(in[idx]);
}

// LSTM weight gate-major permute: wP[pass][n'][k], n' = (h>>4)*64+g*16+(h&15)
__global__ __launch_bounds__(256) void convW_k(
    const float* __restrict__ Wih, const float* __restrict__ Whh,
    u16* __restrict__ wih_p, u16* __restrict__ whh_p)
{
    const int idx = blockIdx.x * 256 + threadIdx.x;
    const int pp = idx >> 18;
    const int np = (idx >> 8) & 1023;
    const int k = idx & 255;
    const int group = np >> 6, g = (np >> 4) & 3, uu = np & 15;
    const int hh = group * 16 + uu;
    const size_t src = (size_t)pp * 262144 + (size_t)(g * 256 + hh) * 256 + k;
    wih_p[idx] = f2bf(Wih[src]);
    whh_p[idx] = f2bf(Whh[src]);
}

__global__ __launch_bounds__(256) void convB_k(
    const float* __restrict__ bih, const float* __restrict__ bhh, float* __restrict__ bp)
{
    const int idx = blockIdx.x * 256 + threadIdx.x;
    const int pp = idx >> 10, np = idx & 1023;
    const int group = np >> 6, g = (np >> 4) & 3, uu = np & 15;
    const int hh = group * 16 + uu;
    bp[idx] = bih[pp * 1024 + g * 256 + hh] + bhh[pp * 1024 + g * 256 + hh];
}

// ---------------------------------------------------------------------------
extern "C" void kernel_launch(void* const* d_in, const int* in_sizes, int n_in,
                              void* d_out, int out_size, void* d_ws, size_t ws_size,
                              hipStream_t stream)
{
    const float* x   = (const float*)d_in[0];
    const float* adj = (const float*)d_in[1];
    const float* Wg0 = (const float*)d_in[2];
    const float* bg0 = (const float*)d_in[3];
    const float* Wg1 = (const float*)d_in[4];
    const float* bg1 = (const float*)d_in[5];
    const float* Wih = (const float*)d_in[6];
    const float* Whh = (const float*)d_in[7];
    const float* bih = (const float*)d_in[8];
    const float* bhh = (const float*)d_in[9];
    float* out = (float*)d_out;

    char* ws = (char*)d_ws;
    u16*   Ax   = (u16*)ws;                         // 67MB: GCN h mirror; p>=2 ping-pong
    u16*   hs0  = Ax;
    u16*   hs1  = (u16*)(ws + 33554432);
    u16*   hsB  = (u16*)(ws + 67108864);            // 67MB: St (GCN) / t-indexed mirror (LSTM)
    float* cst  = (float*)(ws + 134217728);         // 67MB: f32 cell state
    char*  wreg = ws + 201326592;                   // 8MB region
    u16*   adjbf = (u16*)wreg;                      //   GCN phase
    u16*   wihP  = (u16*)wreg;                      //   LSTM phase (adjbf dead)
    u16*   whhP  = (u16*)(wreg + 2097152);
    float* bp    = (float*)(wreg + 4194304);
    u16*   wg0t  = (u16*)(ws + 209715200);
    u16*   wg1t  = (u16*)(ws + 209846272);
    u16*   St    = hsB;

    // ---- casts / weight prep ----
    cast_bf16_k<<<4096, 256, 0, stream>>>(adj, adjbf, 1048576);
    convT_k<<<256, 256, 0, stream>>>(Wg0, wg0t);
    convT_k<<<256, 256, 0, stream>>>(Wg1, wg1t);

    // ---- GCN ----
    bgemm_sup_f32a_k<<<2048, 256, 0, stream>>>(x, wg0t, bg0, St);
    bgemm_adj_k<<<2048, 256, 0, stream>>>(adjbf, St, Ax, 2048, (long long)256 * 2048);
    bgemm_sup_k<<<2048, 256, 0, stream>>>(Ax, wg1t, bg1, St);
    bgemm_adj_k<<<2048, 256, 0, stream>>>(adjbf, St, Ax, 2048, (long long)256 * 2048);

    // ---- LSTM weights (adjbf dead) ----
    convW_k<<<4096, 256, 0, stream>>>(Wih, Whh, wihP, whhP);
    convB_k<<<16, 256, 0, stream>>>(bih, bhh, bp);

    // ---- skip-LSTM passes ----
    for (int p = 1; p <= MAXP; ++p) {
        const int nw = T2 / p;
        const int nwSh = (p == 1) ? 11 : (p == 2) ? 10 : (p == 4) ? 9 : -1;
        const int Nrows = 64 * nw;                  // 131072 / 65536 / 43648 / 32768
        const int cpx = Nrows / 128;                // 1024 / 512 / 341 / 256
        const u16* wihp = wihP + (size_t)(p - 1) * 262144;
        const u16* whhp = whhP + (size_t)(p - 1) * 262144;
        const float* bpp = bp + (size_t)(p - 1) * 1024;
        const u16* xs = (p == 1) ? Ax : hsB;
        for (int j = 0; j < p; ++j) {
            u16* hn = (p == 1) ? hsB : ((j & 1) ? hs1 : hs0);
            const u16* hpv = (j == 0) ? nullptr : ((j & 1) ? hs0 : hs1);
            const int writeH = !(p == MAXP && j == p - 1);
            lstm_step_k<<<cpx * 8, 256, 0, stream>>>(
                xs, hpv, hn, out, cst, wihp, whhp, bpp, nw, nwSh, p, j, cpx, writeH);
        }
        if (p >= 2 && p != MAXP) {
            const u16* hlast = ((p - 1) & 1) ? hs1 : hs0;
            scatter_ax_k<<<(Nrows * 32 + 255) / 256, 256, 0, stream>>>(hlast, hsB, nw, nwSh, p, Nrows);
        }
    }
}

// Round 15
// 1051.570 us; speedup vs baseline: 1.1915x; 1.1915x over previous
//
#include <hip/hip_runtime.h>
#include <hip/hip_bf16.h>

#define T2 2048
#define H2 256
#define BT2 131072          // B*T = 64*2048
#define MAXP 4

typedef __attribute__((ext_vector_type(8))) short bf16x8;
typedef __attribute__((ext_vector_type(4))) float f32x4;
typedef unsigned short u16;

__device__ __forceinline__ u16 f2bf(float f) {
    union { float f; unsigned u; } v; v.f = f;
    unsigned r = (v.u + 0x7FFFu + ((v.u >> 16) & 1u)) >> 16;
    return (u16)r;
}
__device__ __forceinline__ void async16(const void* g, void* l) {
    __builtin_amdgcn_global_load_lds((const __attribute__((address_space(1))) void*)g,
                                     (__attribute__((address_space(3))) void*)l, 16, 0, 0);
}
__device__ __forceinline__ float frcp(float x) { return __builtin_amdgcn_rcpf(x); }
__device__ __forceinline__ float sig_f(float x) { return frcp(1.f + __expf(-x)); }
__device__ __forceinline__ float tanh_f(float x) {
    return 1.f - 2.f * frcp(__expf(2.f * x) + 1.f);
}

// f32 -> bf16 cast, 4 elems/thread (adjacency only)
__global__ __launch_bounds__(256) void cast_bf16_k(
    const float* __restrict__ in, u16* __restrict__ out, int n4)
{
    const int i = blockIdx.x * 256 + threadIdx.x;
    if (i >= n4) return;
    const float4 v = ((const float4*)in)[i];
    ushort4 h;
    h.x = f2bf(v.x); h.y = f2bf(v.y); h.z = f2bf(v.z); h.w = f2bf(v.w);
    ((ushort4*)out)[i] = h;
}

// ---------------------------------------------------------------------------
// Support GEMM 1, fused f32-A (__syncthreads kept: ds_write staging needs
// the lgkm drain): C^T = (x_f32 @ Bt^T + bias) -> bf16 St.
// ---------------------------------------------------------------------------
__global__ __launch_bounds__(256) void bgemm_sup_f32a_k(
    const float* __restrict__ A, const u16* __restrict__ Bt,
    const float* __restrict__ bias, u16* __restrict__ Ct)
{
    __shared__ __align__(16) u16 As[2][128][64];
    __shared__ __align__(16) u16 Bs[2][128][64];
    const int K = 256;

    const int tid = threadIdx.x;
    const int wid = tid >> 6, lane = tid & 63;
    const int wr = wid >> 1, wc = wid & 1;
    const int bx = blockIdx.x >> 1, by = blockIdx.x & 1;
    const int row0 = bx * 128, col0 = by * 128;

    const int srow = tid >> 3;
    const int skA = ((tid ^ srow) & 7) << 3;
    const float* Agf = A + (size_t)(row0 + srow) * K + skA;
    const u16* Bg = Bt + (size_t)(col0 + srow) * K + skA;
    char* ldsA = (char*)&As[0][0][0];
    char* ldsB = (char*)&Bs[0][0][0];
    const int wb = wid << 10;
    const int awr = srow * 128 + (tid & 7) * 16;

    f32x4 acc[4][4];
    #pragma unroll
    for (int i = 0; i < 4; ++i)
        #pragma unroll
        for (int q = 0; q < 4; ++q) acc[i][q] = (f32x4){0.f, 0.f, 0.f, 0.f};

    #pragma unroll
    for (int s = 0; s < 4; ++s) {
        const float4 u0 = *(const float4*)(Agf + (size_t)(s * 32) * K);
        const float4 u1 = *(const float4*)(Agf + (size_t)(s * 32) * K + 4);
        ushort4 h0, h1;
        h0.x = f2bf(u0.x); h0.y = f2bf(u0.y); h0.z = f2bf(u0.z); h0.w = f2bf(u0.w);
        h1.x = f2bf(u1.x); h1.y = f2bf(u1.y); h1.z = f2bf(u1.z); h1.w = f2bf(u1.w);
        *(ushort4*)(ldsA + s * 4096 + awr) = h0;
        *(ushort4*)(ldsA + s * 4096 + awr + 8) = h1;
        async16(Bg + (size_t)(s * 32) * K, ldsB + s * 4096 + wb);
    }
    __syncthreads();

    int cur = 0;
    for (int k0 = 0; k0 < K; k0 += 64) {
        if (k0 + 64 < K) {
            char* dA = ldsA + ((cur ^ 1) << 14);
            char* dB = ldsB + ((cur ^ 1) << 14);
            #pragma unroll
            for (int s = 0; s < 4; ++s) {
                const float4 u0 = *(const float4*)(Agf + (size_t)(s * 32) * K + k0 + 64);
                const float4 u1 = *(const float4*)(Agf + (size_t)(s * 32) * K + k0 + 68);
                ushort4 h0, h1;
                h0.x = f2bf(u0.x); h0.y = f2bf(u0.y); h0.z = f2bf(u0.z); h0.w = f2bf(u0.w);
                h1.x = f2bf(u1.x); h1.y = f2bf(u1.y); h1.z = f2bf(u1.z); h1.w = f2bf(u1.w);
                *(ushort4*)(dA + s * 4096 + awr) = h0;
                *(ushort4*)(dA + s * 4096 + awr + 8) = h1;
                async16(Bg + (size_t)(s * 32) * K + k0 + 64, dB + s * 4096 + wb);
            }
        }
        char* rA = ldsA + (cur << 14);
        char* rB = ldsB + (cur << 14);
        const int mb = lane & 15, g = lane >> 4;
        #pragma unroll
        for (int kk = 0; kk < 2; ++kk) {
            bf16x8 a[4], b[4];
            #pragma unroll
            for (int i = 0; i < 4; ++i) {
                const int r = wr * 64 + i * 16 + mb;
                a[i] = *(const bf16x8*)(rA + r * 128 + ((((kk << 2) + g) ^ (r & 7)) << 4));
            }
            #pragma unroll
            for (int q = 0; q < 4; ++q) {
                const int r = wc * 64 + q * 16 + mb;
                b[q] = *(const bf16x8*)(rB + r * 128 + ((((kk << 2) + g) ^ (r & 7)) << 4));
            }
            #pragma unroll
            for (int i = 0; i < 4; ++i)
                #pragma unroll
                for (int q = 0; q < 4; ++q)
                    acc[i][q] = __builtin_amdgcn_mfma_f32_16x16x32_bf16(a[i], b[q], acc[i][q], 0, 0, 0);
        }
        __syncthreads();
        cur ^= 1;
    }

    #pragma unroll
    for (int i = 0; i < 4; ++i) {
        const int grow = row0 + wr * 64 + i * 16 + ((lane >> 4) << 2);
        #pragma unroll
        for (int q = 0; q < 4; ++q) {
            const int col = col0 + wc * 64 + q * 16 + (lane & 15);
            f32x4 v = acc[i][q];
            const float bv = bias[col];
            ushort4 pk;
            pk.x = f2bf(v[0] + bv); pk.y = f2bf(v[1] + bv);
            pk.z = f2bf(v[2] + bv); pk.w = f2bf(v[3] + bv);
            *(ushort4*)(Ct + ((size_t)((grow >> 11) * 256 + col)) * 2048 + (grow & 2047)) = pk;
        }
    }
}

// ---------------------------------------------------------------------------
// Support GEMM (bf16 A), counted-vmcnt pipeline: C^T = (A @ Bt^T + bias) -> St.
// ---------------------------------------------------------------------------
__global__ __launch_bounds__(256) void bgemm_sup_k(
    const u16* __restrict__ A, const u16* __restrict__ Bt,
    const float* __restrict__ bias, u16* __restrict__ Ct)
{
    __shared__ __align__(16) u16 As[2][128][64];
    __shared__ __align__(16) u16 Bs[2][128][64];
    const int K = 256;

    const int tid = threadIdx.x;
    const int wid = tid >> 6, lane = tid & 63;
    const int wr = wid >> 1, wc = wid & 1;
    const int bx = blockIdx.x >> 1, by = blockIdx.x & 1;
    const int row0 = bx * 128, col0 = by * 128;

    const int srow = tid >> 3;
    const int skA = ((tid ^ srow) & 7) << 3;
    const u16* Ag = A + (size_t)(row0 + srow) * K + skA;
    const u16* Bg = Bt + (size_t)(col0 + srow) * K + skA;
    char* ldsA = (char*)&As[0][0][0];
    char* ldsB = (char*)&Bs[0][0][0];
    const int wb = wid << 10;

    f32x4 acc[4][4];
    #pragma unroll
    for (int i = 0; i < 4; ++i)
        #pragma unroll
        for (int q = 0; q < 4; ++q) acc[i][q] = (f32x4){0.f, 0.f, 0.f, 0.f};

    #pragma unroll
    for (int s = 0; s < 4; ++s) {
        async16(Ag + (size_t)(s * 32) * K, ldsA + s * 4096 + wb);
        async16(Bg + (size_t)(s * 32) * K, ldsB + s * 4096 + wb);
    }

    int cur = 0;
    for (int k0 = 0; k0 < K; k0 += 64) {
        if (k0 + 64 < K) {
            char* dA = ldsA + ((cur ^ 1) << 14);
            char* dB = ldsB + ((cur ^ 1) << 14);
            #pragma unroll
            for (int s = 0; s < 4; ++s) {
                async16(Ag + (size_t)(s * 32) * K + k0 + 64, dA + s * 4096 + wb);
                async16(Bg + (size_t)(s * 32) * K + k0 + 64, dB + s * 4096 + wb);
            }
            asm volatile("s_waitcnt vmcnt(8)" ::: "memory");
        } else {
            asm volatile("s_waitcnt vmcnt(0)" ::: "memory");
        }
        __builtin_amdgcn_s_barrier();
        __builtin_amdgcn_sched_barrier(0);
        char* rA = ldsA + (cur << 14);
        char* rB = ldsB + (cur << 14);
        const int mb = lane & 15, g = lane >> 4;
        #pragma unroll
        for (int kk = 0; kk < 2; ++kk) {
            bf16x8 a[4], b[4];
            #pragma unroll
            for (int i = 0; i < 4; ++i) {
                const int r = wr * 64 + i * 16 + mb;
                a[i] = *(const bf16x8*)(rA + r * 128 + ((((kk << 2) + g) ^ (r & 7)) << 4));
            }
            #pragma unroll
            for (int q = 0; q < 4; ++q) {
                const int r = wc * 64 + q * 16 + mb;
                b[q] = *(const bf16x8*)(rB + r * 128 + ((((kk << 2) + g) ^ (r & 7)) << 4));
            }
            #pragma unroll
            for (int i = 0; i < 4; ++i)
                #pragma unroll
                for (int q = 0; q < 4; ++q)
                    acc[i][q] = __builtin_amdgcn_mfma_f32_16x16x32_bf16(a[i], b[q], acc[i][q], 0, 0, 0);
        }
        __builtin_amdgcn_s_barrier();
        cur ^= 1;
    }

    #pragma unroll
    for (int i = 0; i < 4; ++i) {
        const int grow = row0 + wr * 64 + i * 16 + ((lane >> 4) << 2);
        #pragma unroll
        for (int q = 0; q < 4; ++q) {
            const int col = col0 + wc * 64 + q * 16 + (lane & 15);
            f32x4 v = acc[i][q];
            const float bv = bias[col];
            ushort4 pk;
            pk.x = f2bf(v[0] + bv); pk.y = f2bf(v[1] + bv);
            pk.z = f2bf(v[2] + bv); pk.w = f2bf(v[3] + bv);
            *(ushort4*)(Ct + ((size_t)((grow >> 11) * 256 + col)) * 2048 + (grow & 2047)) = pk;
        }
    }
}

// ---------------------------------------------------------------------------
// Adjacency GEMM: counted-vmcnt pipeline + supertile XCD decode.
// ---------------------------------------------------------------------------
__global__ __launch_bounds__(256) void bgemm_adj_k(
    const u16* __restrict__ A, const u16* __restrict__ Bt,
    u16* __restrict__ Cx, int K, long long bsB)
{
    __shared__ __align__(16) u16 As[2][128][64];
    __shared__ __align__(16) u16 Bs[2][128][64];

    const int tid = threadIdx.x;
    const int wid = tid >> 6, lane = tid & 63;
    const int wr = wid >> 1, wc = wid & 1;

    const int xcd = blockIdx.x & 7, loc = blockIdx.x >> 3;
    const int s = loc >> 4, w = loc & 15;
    const int sg = xcd * 16 + s;
    const int pzg = sg >> 2, bxg = sg & 3;
    const int bx = bxg * 4 + (w >> 2);
    const int pzidx = pzg * 4 + (w & 3);
    const int by = pzidx >> 6, bz = pzidx & 63;

    const int row0 = bx * 128, col0 = by * 128;
    const u16* Bp = Bt + (long long)bz * bsB;

    const int srow = tid >> 3;
    const int skA = ((tid ^ srow) & 7) << 3;
    const u16* Ag = A + (size_t)(row0 + srow) * K + skA;
    const u16* Bg = Bp + (size_t)(col0 + srow) * K + skA;
    char* ldsA = (char*)&As[0][0][0];
    char* ldsB = (char*)&Bs[0][0][0];
    const int wb = wid << 10;

    f32x4 acc[4][4];
    #pragma unroll
    for (int i = 0; i < 4; ++i)
        #pragma unroll
        for (int q = 0; q < 4; ++q) acc[i][q] = (f32x4){0.f, 0.f, 0.f, 0.f};

    #pragma unroll
    for (int s2 = 0; s2 < 4; ++s2) {
        async16(Ag + (size_t)(s2 * 32) * K, ldsA + s2 * 4096 + wb);
        async16(Bg + (size_t)(s2 * 32) * K, ldsB + s2 * 4096 + wb);
    }

    int cur = 0;
    for (int k0 = 0; k0 < K; k0 += 64) {
        if (k0 + 64 < K) {
            char* dA = ldsA + ((cur ^ 1) << 14);
            char* dB = ldsB + ((cur ^ 1) << 14);
            #pragma unroll
            for (int s2 = 0; s2 < 4; ++s2) {
                async16(Ag + (size_t)(s2 * 32) * K + k0 + 64, dA + s2 * 4096 + wb);
                async16(Bg + (size_t)(s2 * 32) * K + k0 + 64, dB + s2 * 4096 + wb);
            }
            asm volatile("s_waitcnt vmcnt(8)" ::: "memory");
        } else {
            asm volatile("s_waitcnt vmcnt(0)" ::: "memory");
        }
        __builtin_amdgcn_s_barrier();
        __builtin_amdgcn_sched_barrier(0);
        char* rA = ldsA + (cur << 14);
        char* rB = ldsB + (cur << 14);
        const int mb = lane & 15, g = lane >> 4;
        #pragma unroll
        for (int kk = 0; kk < 2; ++kk) {
            bf16x8 a[4], b[4];
            #pragma unroll
            for (int i = 0; i < 4; ++i) {
                const int r = wr * 64 + i * 16 + mb;
                a[i] = *(const bf16x8*)(rA + r * 128 + ((((kk << 2) + g) ^ (r & 7)) << 4));
            }
            #pragma unroll
            for (int q = 0; q < 4; ++q) {
                const int r = wc * 64 + q * 16 + mb;
                b[q] = *(const bf16x8*)(rB + r * 128 + ((((kk << 2) + g) ^ (r & 7)) << 4));
            }
            #pragma unroll
            for (int i = 0; i < 4; ++i)
                #pragma unroll
                for (int q = 0; q < 4; ++q)
                    acc[i][q] = __builtin_amdgcn_mfma_f32_16x16x32_bf16(a[i], b[q], acc[i][q], 0, 0, 0);
        }
        __builtin_amdgcn_s_barrier();
        cur ^= 1;
    }

    #pragma unroll
    for (int i = 0; i < 4; ++i) {
        const int grow = row0 + wr * 64 + i * 16 + ((lane >> 4) << 2);
        #pragma unroll
        for (int q = 0; q < 4; ++q) {
            const int col = col0 + wc * 64 + q * 16 + (lane & 15);
            f32x4 v = acc[i][q];
            #pragma unroll
            for (int r = 0; r < 4; ++r)
                Cx[((size_t)bz * 2048 + grow + r) * 256 + col] = f2bf(fmaxf(v[r], 0.f));
        }
    }
}

// is output position tt overwritten by a later pass?
__device__ __forceinline__ bool keep_out(int p, int tt) {
    if (p == 1) return ((tt & 1) == 0) && (tt % 3 != 2) && ((tt & 3) != 3);
    if (p == 2) return (tt % 3 != 2) && ((tt & 3) != 3);
    if (p == 3) return ((tt & 3) != 3);
    return true;
}

// decompose n -> (batch b, window w): shift path for pow2 nw (p=1,2,4)
__device__ __forceinline__ void bw_of(int n, int nw, int nwSh, unsigned& b, int& w) {
    if (nwSh >= 0) { b = (unsigned)n >> nwSh; w = n & (nw - 1); }
    else { b = (unsigned)n / (unsigned)nw; w = n - (int)b * nw; }
}

// ---------------------------------------------------------------------------
// LSTM step, M=128 tile, 512 threads / 8 waves (4 row-groups x 2 col-groups,
// 2x4 frags per wave), counted-vmcnt pipeline (4 loads/thread -> vmcnt(4)),
// 64KB LDS -> 2 blocks/CU = 16 waves/CU (2x the TLP of the 256-thr variant
// at identical LDS). Epilogue in-register; shift-based (b,w) decompose.
// ---------------------------------------------------------------------------
__global__ __launch_bounds__(512) void lstm_step_k(
    const u16* __restrict__ xsrc, const u16* __restrict__ hprev,
    u16* __restrict__ hnext, float* __restrict__ outF, float* __restrict__ cst,
    const u16* __restrict__ wih, const u16* __restrict__ whh,
    const float* __restrict__ biasp, int nw, int nwSh, int p, int j, int cpx, int writeH)
{
    __shared__ __align__(16) u16 As[2][128][64];
    __shared__ __align__(16) u16 Bs[2][128][64];

    const int tid = threadIdx.x;
    const int wid = tid >> 6, lane = tid & 63;
    const int wr = wid >> 1, wc = wid & 1;          // wr 0..3 (32-row), wc 0..1 (64-col)

    const int l = (blockIdx.x & 7) * cpx + (blockIdx.x >> 3);
    const int col0 = (l & 7) << 7;
    const int row0 = (l >> 3) << 7;
    const int first = (j == 0), last = (j == p - 1);

    // staging: wave wid, call s in {0,1}: LDS bytes [s*8192 + wid*1024 + lane*16)
    // -> row r_s = s*64 + wid*8 + (lane>>3), chunk c = lane&7 (holds global
    // chunk c ^ (r_s & 7)).
    const int r0s = wid * 8 + (lane >> 3);
    const int c0 = lane & 7;
    const int sk0 = ((c0 ^ (r0s & 7)) << 3);
    const int sk1 = ((c0 ^ ((r0s + 64) & 7)) << 3);

    const u16* axp[2];
    const u16* hpp[2];
    size_t wrow[2];
    {
        const int rr[2] = {r0s, r0s + 64};
        const int sk[2] = {sk0, sk1};
        #pragma unroll
        for (int s = 0; s < 2; ++s) {
            const int n = row0 + rr[s];
            unsigned b; int w;
            bw_of(n, nw, nwSh, b, w);
            axp[s] = xsrc + ((size_t)b * T2 + (size_t)w * p + j) * H2 + sk[s];
            hpp[s] = hprev ? hprev + (size_t)n * H2 + sk[s] : nullptr;
            wrow[s] = (size_t)(col0 + rr[s]) * H2 + sk[s];
        }
    }
    char* ldsA = (char*)&As[0][0][0];
    char* ldsB = (char*)&Bs[0][0][0];
    const int wb = wid << 10;

    f32x4 acc[2][4];
    #pragma unroll
    for (int i = 0; i < 2; ++i)
        #pragma unroll
        for (int q = 0; q < 4; ++q) acc[i][q] = (f32x4){0.f, 0.f, 0.f, 0.f};

    const int KT = first ? 256 : 512;

    // prologue: stage tile 0 (x-part) into buf 0 -- 4 loads/thread
    #pragma unroll
    for (int s = 0; s < 2; ++s) {
        async16(axp[s], ldsA + s * 8192 + wb);
        async16(wih + wrow[s], ldsB + s * 8192 + wb);
    }

    int cur = 0;
    for (int k0 = 0; k0 < KT; k0 += 64) {
        const int kn = k0 + 64;
        if (kn < KT) {
            char* dA = ldsA + ((cur ^ 1) << 14);
            char* dB = ldsB + ((cur ^ 1) << 14);
            if (kn < 256) {
                #pragma unroll
                for (int s = 0; s < 2; ++s) {
                    async16(axp[s] + kn, dA + s * 8192 + wb);
                    async16(wih + wrow[s] + kn, dB + s * 8192 + wb);
                }
            } else {
                const int kk2 = kn - 256;
                #pragma unroll
                for (int s = 0; s < 2; ++s) {
                    async16(hpp[s] + kk2, dA + s * 8192 + wb);
                    async16(whh + wrow[s] + kk2, dB + s * 8192 + wb);
                }
            }
            asm volatile("s_waitcnt vmcnt(4)" ::: "memory");
        } else {
            asm volatile("s_waitcnt vmcnt(0)" ::: "memory");
        }
        __builtin_amdgcn_s_barrier();
        __builtin_amdgcn_sched_barrier(0);
        char* rA = ldsA + (cur << 14);
        char* rB = ldsB + (cur << 14);
        const int mb = lane & 15, g = lane >> 4;
        #pragma unroll
        for (int kk = 0; kk < 2; ++kk) {
            bf16x8 a[2], b[4];
            #pragma unroll
            for (int i = 0; i < 2; ++i) {
                const int r = wr * 32 + i * 16 + mb;
                a[i] = *(const bf16x8*)(rA + r * 128 + ((((kk << 2) + g) ^ (r & 7)) << 4));
            }
            #pragma unroll
            for (int q = 0; q < 4; ++q) {
                const int r = wc * 64 + q * 16 + mb;
                b[q] = *(const bf16x8*)(rB + r * 128 + ((((kk << 2) + g) ^ (r & 7)) << 4));
            }
            #pragma unroll
            for (int i = 0; i < 2; ++i)
                #pragma unroll
                for (int q = 0; q < 4; ++q)
                    acc[i][q] = __builtin_amdgcn_mfma_f32_16x16x32_bf16(a[i], b[q], acc[i][q], 0, 0, 0);
        }
        __builtin_amdgcn_s_barrier();
        cur ^= 1;
    }

    const int u = lane & 15;
    const int colb = col0 + wc * 64;
    const int hu = (colb >> 2) + u;
    float bq[4];
    #pragma unroll
    for (int q = 0; q < 4; ++q) bq[q] = biasp[colb + q * 16 + u];

    #pragma unroll
    for (int i = 0; i < 2; ++i) {
        const int rbase = row0 + wr * 32 + i * 16 + ((lane >> 4) << 2);
        #pragma unroll
        for (int r = 0; r < 4; ++r) {
            const int n = rbase + r;
            const float gi = acc[i][0][r] + bq[0];
            const float gf = acc[i][1][r] + bq[1];
            const float gg = acc[i][2][r] + bq[2];
            const float go = acc[i][3][r] + bq[3];
            const float si = sig_f(gi), sf = sig_f(gf), so = sig_f(go);
            const float tg = tanh_f(gg);
            const float cp = first ? 0.f : cst[(size_t)n * H2 + hu];
            const float cn = sf * cp + si * tg;
            const float hv = so * tanh_f(cn);
            if (writeH) hnext[(size_t)n * H2 + hu] = f2bf(hv);
            if (last) {
                unsigned b; int w;
                bw_of(n, nw, nwSh, b, w);
                const int tt = w * p + (p - 1);
                if (keep_out(p, tt))
                    outF[((size_t)b * T2 + tt) * H2 + hu] = hv;
            } else {
                cst[(size_t)n * H2 + hu] = cn;
            }
        }
    }
}

// update mirror at window-end positions from deferred hnext (bf16 copy)
__global__ __launch_bounds__(256) void scatter_ax_k(
    const u16* __restrict__ hs, u16* __restrict__ mir, int nw, int nwSh, int p, int Nrows)
{
    const int idx = blockIdx.x * 256 + threadIdx.x;
    if (idx >= Nrows * 32) return;
    const int n = idx >> 5, c8 = (idx & 31) << 3;
    unsigned b; int w;
    bw_of(n, nw, nwSh, b, w);
    *(uint4*)(mir + ((size_t)b * T2 + (size_t)w * p + (p - 1)) * H2 + c8) =
        *(const uint4*)(hs + (size_t)n * H2 + c8);
}

// Wg transpose+cast: out[n][k] = bf16(in[k][n]), 256x256
__global__ __launch_bounds__(256) void convT_k(const float* __restrict__ in, u16* __restrict__ out)
{
    const int idx = blockIdx.x * 256 + threadIdx.x;
    const int r = idx >> 8, c = idx & 255;
    out[(size_t)c * 256 + r] = f2bf(in[idx]);
}

// LSTM weight gate-major permute: wP[pass][n'][k], n' = (h>>4)*64+g*16+(h&15)
__global__ __launch_bounds__(256) void convW_k(
    const float* __restrict__ Wih, const float* __restrict__ Whh,
    u16* __restrict__ wih_p, u16* __restrict__ whh_p)
{
    const int idx = blockIdx.x * 256 + threadIdx.x;
    const int pp = idx >> 18;
    const int np = (idx >> 8) & 1023;
    const int k = idx & 255;
    const int group = np >> 6, g = (np >> 4) & 3, uu = np & 15;
    const int hh = group * 16 + uu;
    const size_t src = (size_t)pp * 262144 + (size_t)(g * 256 + hh) * 256 + k;
    wih_p[idx] = f2bf(Wih[src]);
    whh_p[idx] = f2bf(Whh[src]);
}

__global__ __launch_bounds__(256) void convB_k(
    const float* __restrict__ bih, const float* __restrict__ bhh, float* __restrict__ bp)
{
    const int idx = blockIdx.x * 256 + threadIdx.x;
    const int pp = idx >> 10, np = idx & 1023;
    const int group = np >> 6, g = (np >> 4) & 3, uu = np & 15;
    const int hh = group * 16 + uu;
    bp[idx] = bih[pp * 1024 + g * 256 + hh] + bhh[pp * 1024 + g * 256 + hh];
}

// ---------------------------------------------------------------------------
extern "C" void kernel_launch(void* const* d_in, const int* in_sizes, int n_in,
                              void* d_out, int out_size, void* d_ws, size_t ws_size,
                              hipStream_t stream)
{
    const float* x   = (const float*)d_in[0];
    const float* adj = (const float*)d_in[1];
    const float* Wg0 = (const float*)d_in[2];
    const float* bg0 = (const float*)d_in[3];
    const float* Wg1 = (const float*)d_in[4];
    const float* bg1 = (const float*)d_in[5];
    const float* Wih = (const float*)d_in[6];
    const float* Whh = (const float*)d_in[7];
    const float* bih = (const float*)d_in[8];
    const float* bhh = (const float*)d_in[9];
    float* out = (float*)d_out;

    char* ws = (char*)d_ws;
    u16*   Ax   = (u16*)ws;                         // 67MB: GCN h mirror; p>=2 ping-pong
    u16*   hs0  = Ax;
    u16*   hs1  = (u16*)(ws + 33554432);
    u16*   hsB  = (u16*)(ws + 67108864);            // 67MB: St (GCN) / t-indexed mirror (LSTM)
    float* cst  = (float*)(ws + 134217728);         // 67MB: f32 cell state
    char*  wreg = ws + 201326592;                   // 8MB region
    u16*   adjbf = (u16*)wreg;                      //   GCN phase
    u16*   wihP  = (u16*)wreg;                      //   LSTM phase (adjbf dead)
    u16*   whhP  = (u16*)(wreg + 2097152);
    float* bp    = (float*)(wreg + 4194304);
    u16*   wg0t  = (u16*)(ws + 209715200);
    u16*   wg1t  = (u16*)(ws + 209846272);
    u16*   St    = hsB;

    // ---- casts / weight prep ----
    cast_bf16_k<<<4096, 256, 0, stream>>>(adj, adjbf, 1048576);
    convT_k<<<256, 256, 0, stream>>>(Wg0, wg0t);
    convT_k<<<256, 256, 0, stream>>>(Wg1, wg1t);

    // ---- GCN ----
    bgemm_sup_f32a_k<<<2048, 256, 0, stream>>>(x, wg0t, bg0, St);
    bgemm_adj_k<<<2048, 256, 0, stream>>>(adjbf, St, Ax, 2048, (long long)256 * 2048);
    bgemm_sup_k<<<2048, 256, 0, stream>>>(Ax, wg1t, bg1, St);
    bgemm_adj_k<<<2048, 256, 0, stream>>>(adjbf, St, Ax, 2048, (long long)256 * 2048);

    // ---- LSTM weights (adjbf dead) ----
    convW_k<<<4096, 256, 0, stream>>>(Wih, Whh, wihP, whhP);
    convB_k<<<16, 256, 0, stream>>>(bih, bhh, bp);

    // ---- skip-LSTM passes ----
    for (int p = 1; p <= MAXP; ++p) {
        const int nw = T2 / p;
        const int nwSh = (p == 1) ? 11 : (p == 2) ? 10 : (p == 4) ? 9 : -1;
        const int Nrows = 64 * nw;                  // 131072 / 65536 / 43648 / 32768
        const int cpx = Nrows / 128;                // 1024 / 512 / 341 / 256
        const u16* wihp = wihP + (size_t)(p - 1) * 262144;
        const u16* whhp = whhP + (size_t)(p - 1) * 262144;
        const float* bpp = bp + (size_t)(p - 1) * 1024;
        const u16* xs = (p == 1) ? Ax : hsB;
        for (int j = 0; j < p; ++j) {
            u16* hn = (p == 1) ? hsB : ((j & 1) ? hs1 : hs0);
            const u16* hpv = (j == 0) ? nullptr : ((j & 1) ? hs0 : hs1);
            const int writeH = !(p == MAXP && j == p - 1);
            lstm_step_k<<<cpx * 8, 512, 0, stream>>>(
                xs, hpv, hn, out, cst, wihp, whhp, bpp, nw, nwSh, p, j, cpx, writeH);
        }
        if (p >= 2 && p != MAXP) {
            const u16* hlast = ((p - 1) & 1) ? hs1 : hs0;
            scatter_ax_k<<<(Nrows * 32 + 255) / 256, 256, 0, stream>>>(hlast, hsB, nw, nwSh, p, Nrows);
        }
    }
}

// Round 16
// 1044.608 us; speedup vs baseline: 1.1995x; 1.0067x over previous
//
#include <hip/hip_runtime.h>
#include <hip/hip_bf16.h>

#define T2 2048
#define H2 256
#define BT2 131072          // B*T = 64*2048
#define MAXP 4

typedef __attribute__((ext_vector_type(8))) short bf16x8;
typedef __attribute__((ext_vector_type(4))) float f32x4;
typedef unsigned short u16;

__device__ __forceinline__ u16 f2bf(float f) {
    union { float f; unsigned u; } v; v.f = f;
    unsigned r = (v.u + 0x7FFFu + ((v.u >> 16) & 1u)) >> 16;
    return (u16)r;
}
__device__ __forceinline__ void async16(const void* g, void* l) {
    __builtin_amdgcn_global_load_lds((const __attribute__((address_space(1))) void*)g,
                                     (__attribute__((address_space(3))) void*)l, 16, 0, 0);
}
__device__ __forceinline__ float frcp(float x) { return __builtin_amdgcn_rcpf(x); }
__device__ __forceinline__ float sig_f(float x) { return frcp(1.f + __expf(-x)); }
__device__ __forceinline__ float tanh_f(float x) {
    return 1.f - 2.f * frcp(__expf(2.f * x) + 1.f);
}

// f32 -> bf16 cast, 4 elems/thread (adjacency only)
__global__ __launch_bounds__(256) void cast_bf16_k(
    const float* __restrict__ in, u16* __restrict__ out, int n4)
{
    const int i = blockIdx.x * 256 + threadIdx.x;
    if (i >= n4) return;
    const float4 v = ((const float4*)in)[i];
    ushort4 h;
    h.x = f2bf(v.x); h.y = f2bf(v.y); h.z = f2bf(v.z); h.w = f2bf(v.w);
    ((ushort4*)out)[i] = h;
}

// ---------------------------------------------------------------------------
// Support GEMM 1, fused f32-A (__syncthreads kept: ds_write staging needs
// the lgkm drain): C^T = (x_f32 @ Bt^T + bias) -> bf16 St.
// ---------------------------------------------------------------------------
__global__ __launch_bounds__(256) void bgemm_sup_f32a_k(
    const float* __restrict__ A, const u16* __restrict__ Bt,
    const float* __restrict__ bias, u16* __restrict__ Ct)
{
    __shared__ __align__(16) u16 As[2][128][64];
    __shared__ __align__(16) u16 Bs[2][128][64];
    const int K = 256;

    const int tid = threadIdx.x;
    const int wid = tid >> 6, lane = tid & 63;
    const int wr = wid >> 1, wc = wid & 1;
    const int bx = blockIdx.x >> 1, by = blockIdx.x & 1;
    const int row0 = bx * 128, col0 = by * 128;

    const int srow = tid >> 3;
    const int skA = ((tid ^ srow) & 7) << 3;
    const float* Agf = A + (size_t)(row0 + srow) * K + skA;
    const u16* Bg = Bt + (size_t)(col0 + srow) * K + skA;
    char* ldsA = (char*)&As[0][0][0];
    char* ldsB = (char*)&Bs[0][0][0];
    const int wb = wid << 10;
    const int awr = srow * 128 + (tid & 7) * 16;

    f32x4 acc[4][4];
    #pragma unroll
    for (int i = 0; i < 4; ++i)
        #pragma unroll
        for (int q = 0; q < 4; ++q) acc[i][q] = (f32x4){0.f, 0.f, 0.f, 0.f};

    #pragma unroll
    for (int s = 0; s < 4; ++s) {
        const float4 u0 = *(const float4*)(Agf + (size_t)(s * 32) * K);
        const float4 u1 = *(const float4*)(Agf + (size_t)(s * 32) * K + 4);
        ushort4 h0, h1;
        h0.x = f2bf(u0.x); h0.y = f2bf(u0.y); h0.z = f2bf(u0.z); h0.w = f2bf(u0.w);
        h1.x = f2bf(u1.x); h1.y = f2bf(u1.y); h1.z = f2bf(u1.z); h1.w = f2bf(u1.w);
        *(ushort4*)(ldsA + s * 4096 + awr) = h0;
        *(ushort4*)(ldsA + s * 4096 + awr + 8) = h1;
        async16(Bg + (size_t)(s * 32) * K, ldsB + s * 4096 + wb);
    }
    __syncthreads();

    int cur = 0;
    for (int k0 = 0; k0 < K; k0 += 64) {
        if (k0 + 64 < K) {
            char* dA = ldsA + ((cur ^ 1) << 14);
            char* dB = ldsB + ((cur ^ 1) << 14);
            #pragma unroll
            for (int s = 0; s < 4; ++s) {
                const float4 u0 = *(const float4*)(Agf + (size_t)(s * 32) * K + k0 + 64);
                const float4 u1 = *(const float4*)(Agf + (size_t)(s * 32) * K + k0 + 68);
                ushort4 h0, h1;
                h0.x = f2bf(u0.x); h0.y = f2bf(u0.y); h0.z = f2bf(u0.z); h0.w = f2bf(u0.w);
                h1.x = f2bf(u1.x); h1.y = f2bf(u1.y); h1.z = f2bf(u1.z); h1.w = f2bf(u1.w);
                *(ushort4*)(dA + s * 4096 + awr) = h0;
                *(ushort4*)(dA + s * 4096 + awr + 8) = h1;
                async16(Bg + (size_t)(s * 32) * K + k0 + 64, dB + s * 4096 + wb);
            }
        }
        char* rA = ldsA + (cur << 14);
        char* rB = ldsB + (cur << 14);
        const int mb = lane & 15, g = lane >> 4;
        #pragma unroll
        for (int kk = 0; kk < 2; ++kk) {
            bf16x8 a[4], b[4];
            #pragma unroll
            for (int i = 0; i < 4; ++i) {
                const int r = wr * 64 + i * 16 + mb;
                a[i] = *(const bf16x8*)(rA + r * 128 + ((((kk << 2) + g) ^ (r & 7)) << 4));
            }
            #pragma unroll
            for (int q = 0; q < 4; ++q) {
                const int r = wc * 64 + q * 16 + mb;
                b[q] = *(const bf16x8*)(rB + r * 128 + ((((kk << 2) + g) ^ (r & 7)) << 4));
            }
            #pragma unroll
            for (int i = 0; i < 4; ++i)
                #pragma unroll
                for (int q = 0; q < 4; ++q)
                    acc[i][q] = __builtin_amdgcn_mfma_f32_16x16x32_bf16(a[i], b[q], acc[i][q], 0, 0, 0);
        }
        __syncthreads();
        cur ^= 1;
    }

    #pragma unroll
    for (int i = 0; i < 4; ++i) {
        const int grow = row0 + wr * 64 + i * 16 + ((lane >> 4) << 2);
        #pragma unroll
        for (int q = 0; q < 4; ++q) {
            const int col = col0 + wc * 64 + q * 16 + (lane & 15);
            f32x4 v = acc[i][q];
            const float bv = bias[col];
            ushort4 pk;
            pk.x = f2bf(v[0] + bv); pk.y = f2bf(v[1] + bv);
            pk.z = f2bf(v[2] + bv); pk.w = f2bf(v[3] + bv);
            *(ushort4*)(Ct + ((size_t)((grow >> 11) * 256 + col)) * 2048 + (grow & 2047)) = pk;
        }
    }
}

// ---------------------------------------------------------------------------
// Support GEMM (bf16 A), counted-vmcnt pipeline: C^T = (A @ Bt^T + bias) -> St.
// ---------------------------------------------------------------------------
__global__ __launch_bounds__(256) void bgemm_sup_k(
    const u16* __restrict__ A, const u16* __restrict__ Bt,
    const float* __restrict__ bias, u16* __restrict__ Ct)
{
    __shared__ __align__(16) u16 As[2][128][64];
    __shared__ __align__(16) u16 Bs[2][128][64];
    const int K = 256;

    const int tid = threadIdx.x;
    const int wid = tid >> 6, lane = tid & 63;
    const int wr = wid >> 1, wc = wid & 1;
    const int bx = blockIdx.x >> 1, by = blockIdx.x & 1;
    const int row0 = bx * 128, col0 = by * 128;

    const int srow = tid >> 3;
    const int skA = ((tid ^ srow) & 7) << 3;
    const u16* Ag = A + (size_t)(row0 + srow) * K + skA;
    const u16* Bg = Bt + (size_t)(col0 + srow) * K + skA;
    char* ldsA = (char*)&As[0][0][0];
    char* ldsB = (char*)&Bs[0][0][0];
    const int wb = wid << 10;

    f32x4 acc[4][4];
    #pragma unroll
    for (int i = 0; i < 4; ++i)
        #pragma unroll
        for (int q = 0; q < 4; ++q) acc[i][q] = (f32x4){0.f, 0.f, 0.f, 0.f};

    #pragma unroll
    for (int s = 0; s < 4; ++s) {
        async16(Ag + (size_t)(s * 32) * K, ldsA + s * 4096 + wb);
        async16(Bg + (size_t)(s * 32) * K, ldsB + s * 4096 + wb);
    }

    int cur = 0;
    for (int k0 = 0; k0 < K; k0 += 64) {
        if (k0 + 64 < K) {
            char* dA = ldsA + ((cur ^ 1) << 14);
            char* dB = ldsB + ((cur ^ 1) << 14);
            #pragma unroll
            for (int s = 0; s < 4; ++s) {
                async16(Ag + (size_t)(s * 32) * K + k0 + 64, dA + s * 4096 + wb);
                async16(Bg + (size_t)(s * 32) * K + k0 + 64, dB + s * 4096 + wb);
            }
            asm volatile("s_waitcnt vmcnt(8)" ::: "memory");
        } else {
            asm volatile("s_waitcnt vmcnt(0)" ::: "memory");
        }
        __builtin_amdgcn_s_barrier();
        __builtin_amdgcn_sched_barrier(0);
        char* rA = ldsA + (cur << 14);
        char* rB = ldsB + (cur << 14);
        const int mb = lane & 15, g = lane >> 4;
        #pragma unroll
        for (int kk = 0; kk < 2; ++kk) {
            bf16x8 a[4], b[4];
            #pragma unroll
            for (int i = 0; i < 4; ++i) {
                const int r = wr * 64 + i * 16 + mb;
                a[i] = *(const bf16x8*)(rA + r * 128 + ((((kk << 2) + g) ^ (r & 7)) << 4));
            }
            #pragma unroll
            for (int q = 0; q < 4; ++q) {
                const int r = wc * 64 + q * 16 + mb;
                b[q] = *(const bf16x8*)(rB + r * 128 + ((((kk << 2) + g) ^ (r & 7)) << 4));
            }
            #pragma unroll
            for (int i = 0; i < 4; ++i)
                #pragma unroll
                for (int q = 0; q < 4; ++q)
                    acc[i][q] = __builtin_amdgcn_mfma_f32_16x16x32_bf16(a[i], b[q], acc[i][q], 0, 0, 0);
        }
        __builtin_amdgcn_s_barrier();
        cur ^= 1;
    }

    #pragma unroll
    for (int i = 0; i < 4; ++i) {
        const int grow = row0 + wr * 64 + i * 16 + ((lane >> 4) << 2);
        #pragma unroll
        for (int q = 0; q < 4; ++q) {
            const int col = col0 + wc * 64 + q * 16 + (lane & 15);
            f32x4 v = acc[i][q];
            const float bv = bias[col];
            ushort4 pk;
            pk.x = f2bf(v[0] + bv); pk.y = f2bf(v[1] + bv);
            pk.z = f2bf(v[2] + bv); pk.w = f2bf(v[3] + bv);
            *(ushort4*)(Ct + ((size_t)((grow >> 11) * 256 + col)) * 2048 + (grow & 2047)) = pk;
        }
    }
}

// ---------------------------------------------------------------------------
// Adjacency GEMM: 512 threads / 8 waves (4 row-groups x 2 col-groups, 2x4
// frags/wave), counted-vmcnt pipeline (4 loads/thread -> vmcnt(4)), 64KB LDS
// -> 2 blocks/CU = 16 waves/CU. Supertile XCD decode unchanged.
// ---------------------------------------------------------------------------
__global__ __launch_bounds__(512) void bgemm_adj_k(
    const u16* __restrict__ A, const u16* __restrict__ Bt,
    u16* __restrict__ Cx, int K, long long bsB)
{
    __shared__ __align__(16) u16 As[2][128][64];
    __shared__ __align__(16) u16 Bs[2][128][64];

    const int tid = threadIdx.x;
    const int wid = tid >> 6, lane = tid & 63;      // wid 0..7
    const int wr = wid >> 1, wc = wid & 1;          // wr 0..3 (32-row), wc 0..1 (64-col)

    const int xcd = blockIdx.x & 7, loc = blockIdx.x >> 3;
    const int s = loc >> 4, w = loc & 15;
    const int sg = xcd * 16 + s;
    const int pzg = sg >> 2, bxg = sg & 3;
    const int bx = bxg * 4 + (w >> 2);
    const int pzidx = pzg * 4 + (w & 3);
    const int by = pzidx >> 6, bz = pzidx & 63;

    const int row0 = bx * 128, col0 = by * 128;
    const u16* Bp = Bt + (long long)bz * bsB;

    // staging: wave wid, seg s in {0,1}: row r = s*64 + wid*8 + (lane>>3),
    // phys chunk c = lane&7 holds global chunk c ^ (r&7). LDS dest linear.
    const int r0s = wid * 8 + (lane >> 3);
    const int c0 = lane & 7;
    const int sk0 = ((c0 ^ (r0s & 7)) << 3);
    const int sk1 = ((c0 ^ ((r0s + 64) & 7)) << 3);
    const u16* Ag0 = A + (size_t)(row0 + r0s) * K + sk0;
    const u16* Ag1 = A + (size_t)(row0 + r0s + 64) * K + sk1;
    const u16* Bg0 = Bp + (size_t)(col0 + r0s) * K + sk0;
    const u16* Bg1 = Bp + (size_t)(col0 + r0s + 64) * K + sk1;
    char* ldsA = (char*)&As[0][0][0];
    char* ldsB = (char*)&Bs[0][0][0];
    const int wb = wid << 10;

    f32x4 acc[2][4];
    #pragma unroll
    for (int i = 0; i < 2; ++i)
        #pragma unroll
        for (int q = 0; q < 4; ++q) acc[i][q] = (f32x4){0.f, 0.f, 0.f, 0.f};

    // prologue: stage tile 0 into buf 0 -- 4 loads/thread
    async16(Ag0, ldsA + wb);
    async16(Ag1, ldsA + 8192 + wb);
    async16(Bg0, ldsB + wb);
    async16(Bg1, ldsB + 8192 + wb);

    int cur = 0;
    for (int k0 = 0; k0 < K; k0 += 64) {
        if (k0 + 64 < K) {
            char* dA = ldsA + ((cur ^ 1) << 14);
            char* dB = ldsB + ((cur ^ 1) << 14);
            async16(Ag0 + k0 + 64, dA + wb);
            async16(Ag1 + k0 + 64, dA + 8192 + wb);
            async16(Bg0 + k0 + 64, dB + wb);
            async16(Bg1 + k0 + 64, dB + 8192 + wb);
            asm volatile("s_waitcnt vmcnt(4)" ::: "memory");
        } else {
            asm volatile("s_waitcnt vmcnt(0)" ::: "memory");
        }
        __builtin_amdgcn_s_barrier();
        __builtin_amdgcn_sched_barrier(0);
        char* rA = ldsA + (cur << 14);
        char* rB = ldsB + (cur << 14);
        const int mb = lane & 15, g = lane >> 4;
        #pragma unroll
        for (int kk = 0; kk < 2; ++kk) {
            bf16x8 a[2], b[4];
            #pragma unroll
            for (int i = 0; i < 2; ++i) {
                const int r = wr * 32 + i * 16 + mb;
                a[i] = *(const bf16x8*)(rA + r * 128 + ((((kk << 2) + g) ^ (r & 7)) << 4));
            }
            #pragma unroll
            for (int q = 0; q < 4; ++q) {
                const int r = wc * 64 + q * 16 + mb;
                b[q] = *(const bf16x8*)(rB + r * 128 + ((((kk << 2) + g) ^ (r & 7)) << 4));
            }
            #pragma unroll
            for (int i = 0; i < 2; ++i)
                #pragma unroll
                for (int q = 0; q < 4; ++q)
                    acc[i][q] = __builtin_amdgcn_mfma_f32_16x16x32_bf16(a[i], b[q], acc[i][q], 0, 0, 0);
        }
        __builtin_amdgcn_s_barrier();
        cur ^= 1;
    }

    #pragma unroll
    for (int i = 0; i < 2; ++i) {
        const int grow = row0 + wr * 32 + i * 16 + ((lane >> 4) << 2);
        #pragma unroll
        for (int q = 0; q < 4; ++q) {
            const int col = col0 + wc * 64 + q * 16 + (lane & 15);
            f32x4 v = acc[i][q];
            #pragma unroll
            for (int r = 0; r < 4; ++r)
                Cx[((size_t)bz * 2048 + grow + r) * 256 + col] = f2bf(fmaxf(v[r], 0.f));
        }
    }
}

// is output position tt overwritten by a later pass?
__device__ __forceinline__ bool keep_out(int p, int tt) {
    if (p == 1) return ((tt & 1) == 0) && (tt % 3 != 2) && ((tt & 3) != 3);
    if (p == 2) return (tt % 3 != 2) && ((tt & 3) != 3);
    if (p == 3) return ((tt & 3) != 3);
    return true;
}

// decompose n -> (batch b, window w): shift path for pow2 nw (p=1,2,4)
__device__ __forceinline__ void bw_of(int n, int nw, int nwSh, unsigned& b, int& w) {
    if (nwSh >= 0) { b = (unsigned)n >> nwSh; w = n & (nw - 1); }
    else { b = (unsigned)n / (unsigned)nw; w = n - (int)b * nw; }
}

// ---------------------------------------------------------------------------
// LSTM step, M=128 tile, 512 threads / 8 waves, counted-vmcnt pipeline
// (4 loads/thread -> vmcnt(4)), 64KB LDS -> 2 blocks/CU = 16 waves/CU.
// ---------------------------------------------------------------------------
__global__ __launch_bounds__(512) void lstm_step_k(
    const u16* __restrict__ xsrc, const u16* __restrict__ hprev,
    u16* __restrict__ hnext, float* __restrict__ outF, float* __restrict__ cst,
    const u16* __restrict__ wih, const u16* __restrict__ whh,
    const float* __restrict__ biasp, int nw, int nwSh, int p, int j, int cpx, int writeH)
{
    __shared__ __align__(16) u16 As[2][128][64];
    __shared__ __align__(16) u16 Bs[2][128][64];

    const int tid = threadIdx.x;
    const int wid = tid >> 6, lane = tid & 63;
    const int wr = wid >> 1, wc = wid & 1;          // wr 0..3 (32-row), wc 0..1 (64-col)

    const int l = (blockIdx.x & 7) * cpx + (blockIdx.x >> 3);
    const int col0 = (l & 7) << 7;
    const int row0 = (l >> 3) << 7;
    const int first = (j == 0), last = (j == p - 1);

    const int r0s = wid * 8 + (lane >> 3);
    const int c0 = lane & 7;
    const int sk0 = ((c0 ^ (r0s & 7)) << 3);
    const int sk1 = ((c0 ^ ((r0s + 64) & 7)) << 3);

    const u16* axp[2];
    const u16* hpp[2];
    size_t wrow[2];
    {
        const int rr[2] = {r0s, r0s + 64};
        const int sk[2] = {sk0, sk1};
        #pragma unroll
        for (int s = 0; s < 2; ++s) {
            const int n = row0 + rr[s];
            unsigned b; int w;
            bw_of(n, nw, nwSh, b, w);
            axp[s] = xsrc + ((size_t)b * T2 + (size_t)w * p + j) * H2 + sk[s];
            hpp[s] = hprev ? hprev + (size_t)n * H2 + sk[s] : nullptr;
            wrow[s] = (size_t)(col0 + rr[s]) * H2 + sk[s];
        }
    }
    char* ldsA = (char*)&As[0][0][0];
    char* ldsB = (char*)&Bs[0][0][0];
    const int wb = wid << 10;

    f32x4 acc[2][4];
    #pragma unroll
    for (int i = 0; i < 2; ++i)
        #pragma unroll
        for (int q = 0; q < 4; ++q) acc[i][q] = (f32x4){0.f, 0.f, 0.f, 0.f};

    const int KT = first ? 256 : 512;

    // prologue: stage tile 0 (x-part) into buf 0 -- 4 loads/thread
    #pragma unroll
    for (int s = 0; s < 2; ++s) {
        async16(axp[s], ldsA + s * 8192 + wb);
        async16(wih + wrow[s], ldsB + s * 8192 + wb);
    }

    int cur = 0;
    for (int k0 = 0; k0 < KT; k0 += 64) {
        const int kn = k0 + 64;
        if (kn < KT) {
            char* dA = ldsA + ((cur ^ 1) << 14);
            char* dB = ldsB + ((cur ^ 1) << 14);
            if (kn < 256) {
                #pragma unroll
                for (int s = 0; s < 2; ++s) {
                    async16(axp[s] + kn, dA + s * 8192 + wb);
                    async16(wih + wrow[s] + kn, dB + s * 8192 + wb);
                }
            } else {
                const int kk2 = kn - 256;
                #pragma unroll
                for (int s = 0; s < 2; ++s) {
                    async16(hpp[s] + kk2, dA + s * 8192 + wb);
                    async16(whh + wrow[s] + kk2, dB + s * 8192 + wb);
                }
            }
            asm volatile("s_waitcnt vmcnt(4)" ::: "memory");
        } else {
            asm volatile("s_waitcnt vmcnt(0)" ::: "memory");
        }
        __builtin_amdgcn_s_barrier();
        __builtin_amdgcn_sched_barrier(0);
        char* rA = ldsA + (cur << 14);
        char* rB = ldsB + (cur << 14);
        const int mb = lane & 15, g = lane >> 4;
        #pragma unroll
        for (int kk = 0; kk < 2; ++kk) {
            bf16x8 a[2], b[4];
            #pragma unroll
            for (int i = 0; i < 2; ++i) {
                const int r = wr * 32 + i * 16 + mb;
                a[i] = *(const bf16x8*)(rA + r * 128 + ((((kk << 2) + g) ^ (r & 7)) << 4));
            }
            #pragma unroll
            for (int q = 0; q < 4; ++q) {
                const int r = wc * 64 + q * 16 + mb;
                b[q] = *(const bf16x8*)(rB + r * 128 + ((((kk << 2) + g) ^ (r & 7)) << 4));
            }
            #pragma unroll
            for (int i = 0; i < 2; ++i)
                #pragma unroll
                for (int q = 0; q < 4; ++q)
                    acc[i][q] = __builtin_amdgcn_mfma_f32_16x16x32_bf16(a[i], b[q], acc[i][q], 0, 0, 0);
        }
        __builtin_amdgcn_s_barrier();
        cur ^= 1;
    }

    const int u = lane & 15;
    const int colb = col0 + wc * 64;
    const int hu = (colb >> 2) + u;
    float bq[4];
    #pragma unroll
    for (int q = 0; q < 4; ++q) bq[q] = biasp[colb + q * 16 + u];

    #pragma unroll
    for (int i = 0; i < 2; ++i) {
        const int rbase = row0 + wr * 32 + i * 16 + ((lane >> 4) << 2);
        #pragma unroll
        for (int r = 0; r < 4; ++r) {
            const int n = rbase + r;
            const float gi = acc[i][0][r] + bq[0];
            const float gf = acc[i][1][r] + bq[1];
            const float gg = acc[i][2][r] + bq[2];
            const float go = acc[i][3][r] + bq[3];
            const float si = sig_f(gi), sf = sig_f(gf), so = sig_f(go);
            const float tg = tanh_f(gg);
            const float cp = first ? 0.f : cst[(size_t)n * H2 + hu];
            const float cn = sf * cp + si * tg;
            const float hv = so * tanh_f(cn);
            if (writeH) hnext[(size_t)n * H2 + hu] = f2bf(hv);
            if (last) {
                unsigned b; int w;
                bw_of(n, nw, nwSh, b, w);
                const int tt = w * p + (p - 1);
                if (keep_out(p, tt))
                    outF[((size_t)b * T2 + tt) * H2 + hu] = hv;
            } else {
                cst[(size_t)n * H2 + hu] = cn;
            }
        }
    }
}

// update mirror at window-end positions from deferred hnext (bf16 copy)
__global__ __launch_bounds__(256) void scatter_ax_k(
    const u16* __restrict__ hs, u16* __restrict__ mir, int nw, int nwSh, int p, int Nrows)
{
    const int idx = blockIdx.x * 256 + threadIdx.x;
    if (idx >= Nrows * 32) return;
    const int n = idx >> 5, c8 = (idx & 31) << 3;
    unsigned b; int w;
    bw_of(n, nw, nwSh, b, w);
    *(uint4*)(mir + ((size_t)b * T2 + (size_t)w * p + (p - 1)) * H2 + c8) =
        *(const uint4*)(hs + (size_t)n * H2 + c8);
}

// Wg transpose+cast: out[n][k] = bf16(in[k][n]), 256x256
__global__ __launch_bounds__(256) void convT_k(const float* __restrict__ in, u16* __restrict__ out)
{
    const int idx = blockIdx.x * 256 + threadIdx.x;
    const int r = idx >> 8, c = idx & 255;
    out[(size_t)c * 256 + r] = f2bf(in[idx]);
}

// LSTM weight gate-major permute: wP[pass][n'][k], n' = (h>>4)*64+g*16+(h&15)
__global__ __launch_bounds__(256) void convW_k(
    const float* __restrict__ Wih, const float* __restrict__ Whh,
    u16* __restrict__ wih_p, u16* __restrict__ whh_p)
{
    const int idx = blockIdx.x * 256 + threadIdx.x;
    const int pp = idx >> 18;
    const int np = (idx >> 8) & 1023;
    const int k = idx & 255;
    const int group = np >> 6, g = (np >> 4) & 3, uu = np & 15;
    const int hh = group * 16 + uu;
    const size_t src = (size_t)pp * 262144 + (size_t)(g * 256 + hh) * 256 + k;
    wih_p[idx] = f2bf(Wih[src]);
    whh_p[idx] = f2bf(Whh[src]);
}

__global__ __launch_bounds__(256) void convB_k(
    const float* __restrict__ bih, const float* __restrict__ bhh, float* __restrict__ bp)
{
    const int idx = blockIdx.x * 256 + threadIdx.x;
    const int pp = idx >> 10, np = idx & 1023;
    const int group = np >> 6, g = (np >> 4) & 3, uu = np & 15;
    const int hh = group * 16 + uu;
    bp[idx] = bih[pp * 1024 + g * 256 + hh] + bhh[pp * 1024 + g * 256 + hh];
}

// ---------------------------------------------------------------------------
extern "C" void kernel_launch(void* const* d_in, const int* in_sizes, int n_in,
                              void* d_out, int out_size, void* d_ws, size_t ws_size,
                              hipStream_t stream)
{
    const float* x   = (const float*)d_in[0];
    const float* adj = (const float*)d_in[1];
    const float* Wg0 = (const float*)d_in[2];
    const float* bg0 = (const float*)d_in[3];
    const float* Wg1 = (const float*)d_in[4];
    const float* bg1 = (const float*)d_in[5];
    const float* Wih = (const float*)d_in[6];
    const float* Whh = (const float*)d_in[7];
    const float* bih = (const float*)d_in[8];
    const float* bhh = (const float*)d_in[9];
    float* out = (float*)d_out;

    char* ws = (char*)d_ws;
    u16*   Ax   = (u16*)ws;                         // 67MB: GCN h mirror; p>=2 ping-pong
    u16*   hs0  = Ax;
    u16*   hs1  = (u16*)(ws + 33554432);
    u16*   hsB  = (u16*)(ws + 67108864);            // 67MB: St (GCN) / t-indexed mirror (LSTM)
    float* cst  = (float*)(ws + 134217728);         // 67MB: f32 cell state
    char*  wreg = ws + 201326592;                   // 8MB region
    u16*   adjbf = (u16*)wreg;                      //   GCN phase
    u16*   wihP  = (u16*)wreg;                      //   LSTM phase (adjbf dead)
    u16*   whhP  = (u16*)(wreg + 2097152);
    float* bp    = (float*)(wreg + 4194304);
    u16*   wg0t  = (u16*)(ws + 209715200);
    u16*   wg1t  = (u16*)(ws + 209846272);
    u16*   St    = hsB;

    // ---- casts / weight prep ----
    cast_bf16_k<<<4096, 256, 0, stream>>>(adj, adjbf, 1048576);
    convT_k<<<256, 256, 0, stream>>>(Wg0, wg0t);
    convT_k<<<256, 256, 0, stream>>>(Wg1, wg1t);

    // ---- GCN ----
    bgemm_sup_f32a_k<<<2048, 256, 0, stream>>>(x, wg0t, bg0, St);
    bgemm_adj_k<<<2048, 512, 0, stream>>>(adjbf, St, Ax, 2048, (long long)256 * 2048);
    bgemm_sup_k<<<2048, 256, 0, stream>>>(Ax, wg1t, bg1, St);
    bgemm_adj_k<<<2048, 512, 0, stream>>>(adjbf, St, Ax, 2048, (long long)256 * 2048);

    // ---- LSTM weights (adjbf dead) ----
    convW_k<<<4096, 256, 0, stream>>>(Wih, Whh, wihP, whhP);
    convB_k<<<16, 256, 0, stream>>>(bih, bhh, bp);

    // ---- skip-LSTM passes ----
    for (int p = 1; p <= MAXP; ++p) {
        const int nw = T2 / p;
        const int nwSh = (p == 1) ? 11 : (p == 2) ? 10 : (p == 4) ? 9 : -1;
        const int Nrows = 64 * nw;                  // 131072 / 65536 / 43648 / 32768
        const int cpx = Nrows / 128;                // 1024 / 512 / 341 / 256
        const u16* wihp = wihP + (size_t)(p - 1) * 262144;
        const u16* whhp = whhP + (size_t)(p - 1) * 262144;
        const float* bpp = bp + (size_t)(p - 1) * 1024;
        const u16* xs = (p == 1) ? Ax : hsB;
        for (int j = 0; j < p; ++j) {
            u16* hn = (p == 1) ? hsB : ((j & 1) ? hs1 : hs0);
            const u16* hpv = (j == 0) ? nullptr : ((j & 1) ? hs0 : hs1);
            const int writeH = !(p == MAXP && j == p - 1);
            lstm_step_k<<<cpx * 8, 512, 0, stream>>>(
                xs, hpv, hn, out, cst, wihp, whhp, bpp, nw, nwSh, p, j, cpx, writeH);
        }
        if (p >= 2 && p != MAXP) {
            const u16* hlast = ((p - 1) & 1) ? hs1 : hs0;
            scatter_ax_k<<<(Nrows * 32 + 255) / 256, 256, 0, stream>>>(hlast, hsB, nw, nwSh, p, Nrows);
        }
    }
}

// Round 17
// 1040.855 us; speedup vs baseline: 1.2038x; 1.0036x over previous
//
#include <hip/hip_runtime.h>
#include <hip/hip_bf16.h>

#define T2 2048
#define H2 256
#define BT2 131072          // B*T = 64*2048
#define MAXP 4

typedef __attribute__((ext_vector_type(8))) short bf16x8;
typedef __attribute__((ext_vector_type(4))) float f32x4;
typedef unsigned short u16;

__device__ __forceinline__ u16 f2bf(float f) {
    union { float f; unsigned u; } v; v.f = f;
    unsigned r = (v.u + 0x7FFFu + ((v.u >> 16) & 1u)) >> 16;
    return (u16)r;
}
__device__ __forceinline__ void async16(const void* g, void* l) {
    __builtin_amdgcn_global_load_lds((const __attribute__((address_space(1))) void*)g,
                                     (__attribute__((address_space(3))) void*)l, 16, 0, 0);
}
__device__ __forceinline__ float frcp(float x) { return __builtin_amdgcn_rcpf(x); }
__device__ __forceinline__ float sig_f(float x) { return frcp(1.f + __expf(-x)); }
__device__ __forceinline__ float tanh_f(float x) {
    return 1.f - 2.f * frcp(__expf(2.f * x) + 1.f);
}

// f32 -> bf16 cast, 4 elems/thread (adjacency only)
__global__ __launch_bounds__(256) void cast_bf16_k(
    const float* __restrict__ in, u16* __restrict__ out, int n4)
{
    const int i = blockIdx.x * 256 + threadIdx.x;
    if (i >= n4) return;
    const float4 v = ((const float4*)in)[i];
    ushort4 h;
    h.x = f2bf(v.x); h.y = f2bf(v.y); h.z = f2bf(v.z); h.w = f2bf(v.w);
    ((ushort4*)out)[i] = h;
}

// ---------------------------------------------------------------------------
// Support GEMM 1, fused f32-A, 512 threads / 8 waves. A staged by
// reg-convert + swizzled ds_write (2 rows/thread); B via global_load_lds.
// __syncthreads kept (ds_write needs the lgkm drain). K = 256.
// C^T = (x_f32 @ Bt^T + bias) -> bf16 St[b][col][t].
// ---------------------------------------------------------------------------
__global__ __launch_bounds__(512) void bgemm_sup_f32a_k(
    const float* __restrict__ A, const u16* __restrict__ Bt,
    const float* __restrict__ bias, u16* __restrict__ Ct)
{
    __shared__ __align__(16) u16 As[2][128][64];
    __shared__ __align__(16) u16 Bs[2][128][64];
    const int K = 256;

    const int tid = threadIdx.x;
    const int wid = tid >> 6, lane = tid & 63;
    const int wr = wid >> 1, wc = wid & 1;          // wr 0..3, wc 0..1
    const int bx = blockIdx.x >> 1, by = blockIdx.x & 1;
    const int row0 = bx * 128, col0 = by * 128;

    // staging: rows r0s and r0s+64 (same XOR phase: 64 % 8 == 0)
    const int r0s = wid * 8 + (lane >> 3);          // 0..63
    const int c0 = lane & 7;
    const int skc = ((c0 ^ (r0s & 7)) << 3);        // swizzled k-elem offset
    const float* Agf0 = A + (size_t)(row0 + r0s) * K + skc;
    const float* Agf1 = A + (size_t)(row0 + r0s + 64) * K + skc;
    const u16* Bg0 = Bt + (size_t)(col0 + r0s) * K + skc;
    const u16* Bg1 = Bt + (size_t)(col0 + r0s + 64) * K + skc;
    char* ldsA = (char*)&As[0][0][0];
    char* ldsB = (char*)&Bs[0][0][0];
    const int wb = wid << 10;
    const int awr0 = r0s * 128 + c0 * 16;
    const int awr1 = (r0s + 64) * 128 + c0 * 16;

    f32x4 acc[2][4];
    #pragma unroll
    for (int i = 0; i < 2; ++i)
        #pragma unroll
        for (int q = 0; q < 4; ++q) acc[i][q] = (f32x4){0.f, 0.f, 0.f, 0.f};

    // prologue: stage tile 0 into buf 0
    {
        const float4 u0 = *(const float4*)(Agf0);
        const float4 u1 = *(const float4*)(Agf0 + 4);
        const float4 u2 = *(const float4*)(Agf1);
        const float4 u3 = *(const float4*)(Agf1 + 4);
        ushort4 h0, h1, h2, h3;
        h0.x = f2bf(u0.x); h0.y = f2bf(u0.y); h0.z = f2bf(u0.z); h0.w = f2bf(u0.w);
        h1.x = f2bf(u1.x); h1.y = f2bf(u1.y); h1.z = f2bf(u1.z); h1.w = f2bf(u1.w);
        h2.x = f2bf(u2.x); h2.y = f2bf(u2.y); h2.z = f2bf(u2.z); h2.w = f2bf(u2.w);
        h3.x = f2bf(u3.x); h3.y = f2bf(u3.y); h3.z = f2bf(u3.z); h3.w = f2bf(u3.w);
        *(ushort4*)(ldsA + awr0) = h0;
        *(ushort4*)(ldsA + awr0 + 8) = h1;
        *(ushort4*)(ldsA + awr1) = h2;
        *(ushort4*)(ldsA + awr1 + 8) = h3;
        async16(Bg0, ldsB + wb);
        async16(Bg1, ldsB + 8192 + wb);
    }
    __syncthreads();

    int cur = 0;
    for (int k0 = 0; k0 < K; k0 += 64) {
        if (k0 + 64 < K) {
            char* dA = ldsA + ((cur ^ 1) << 14);
            char* dB = ldsB + ((cur ^ 1) << 14);
            const float4 u0 = *(const float4*)(Agf0 + k0 + 64);
            const float4 u1 = *(const float4*)(Agf0 + k0 + 68);
            const float4 u2 = *(const float4*)(Agf1 + k0 + 64);
            const float4 u3 = *(const float4*)(Agf1 + k0 + 68);
            ushort4 h0, h1, h2, h3;
            h0.x = f2bf(u0.x); h0.y = f2bf(u0.y); h0.z = f2bf(u0.z); h0.w = f2bf(u0.w);
            h1.x = f2bf(u1.x); h1.y = f2bf(u1.y); h1.z = f2bf(u1.z); h1.w = f2bf(u1.w);
            h2.x = f2bf(u2.x); h2.y = f2bf(u2.y); h2.z = f2bf(u2.z); h2.w = f2bf(u2.w);
            h3.x = f2bf(u3.x); h3.y = f2bf(u3.y); h3.z = f2bf(u3.z); h3.w = f2bf(u3.w);
            *(ushort4*)(dA + awr0) = h0;
            *(ushort4*)(dA + awr0 + 8) = h1;
            *(ushort4*)(dA + awr1) = h2;
            *(ushort4*)(dA + awr1 + 8) = h3;
            async16(Bg0 + k0 + 64, dB + wb);
            async16(Bg1 + k0 + 64, dB + 8192 + wb);
        }
        char* rA = ldsA + (cur << 14);
        char* rB = ldsB + (cur << 14);
        const int mb = lane & 15, g = lane >> 4;
        #pragma unroll
        for (int kk = 0; kk < 2; ++kk) {
            bf16x8 a[2], b[4];
            #pragma unroll
            for (int i = 0; i < 2; ++i) {
                const int r = wr * 32 + i * 16 + mb;
                a[i] = *(const bf16x8*)(rA + r * 128 + ((((kk << 2) + g) ^ (r & 7)) << 4));
            }
            #pragma unroll
            for (int q = 0; q < 4; ++q) {
                const int r = wc * 64 + q * 16 + mb;
                b[q] = *(const bf16x8*)(rB + r * 128 + ((((kk << 2) + g) ^ (r & 7)) << 4));
            }
            #pragma unroll
            for (int i = 0; i < 2; ++i)
                #pragma unroll
                for (int q = 0; q < 4; ++q)
                    acc[i][q] = __builtin_amdgcn_mfma_f32_16x16x32_bf16(a[i], b[q], acc[i][q], 0, 0, 0);
        }
        __syncthreads();
        cur ^= 1;
    }

    #pragma unroll
    for (int i = 0; i < 2; ++i) {
        const int grow = row0 + wr * 32 + i * 16 + ((lane >> 4) << 2);
        #pragma unroll
        for (int q = 0; q < 4; ++q) {
            const int col = col0 + wc * 64 + q * 16 + (lane & 15);
            f32x4 v = acc[i][q];
            const float bv = bias[col];
            ushort4 pk;
            pk.x = f2bf(v[0] + bv); pk.y = f2bf(v[1] + bv);
            pk.z = f2bf(v[2] + bv); pk.w = f2bf(v[3] + bv);
            *(ushort4*)(Ct + ((size_t)((grow >> 11) * 256 + col)) * 2048 + (grow & 2047)) = pk;
        }
    }
}

// ---------------------------------------------------------------------------
// Support GEMM (bf16 A), 512 threads / 8 waves, counted-vmcnt pipeline
// (4 loads/thread -> vmcnt(4)). K = 256. C^T -> bf16 St.
// ---------------------------------------------------------------------------
__global__ __launch_bounds__(512) void bgemm_sup_k(
    const u16* __restrict__ A, const u16* __restrict__ Bt,
    const float* __restrict__ bias, u16* __restrict__ Ct)
{
    __shared__ __align__(16) u16 As[2][128][64];
    __shared__ __align__(16) u16 Bs[2][128][64];
    const int K = 256;

    const int tid = threadIdx.x;
    const int wid = tid >> 6, lane = tid & 63;
    const int wr = wid >> 1, wc = wid & 1;
    const int bx = blockIdx.x >> 1, by = blockIdx.x & 1;
    const int row0 = bx * 128, col0 = by * 128;

    const int r0s = wid * 8 + (lane >> 3);
    const int c0 = lane & 7;
    const int skc = ((c0 ^ (r0s & 7)) << 3);
    const u16* Ag0 = A + (size_t)(row0 + r0s) * K + skc;
    const u16* Ag1 = A + (size_t)(row0 + r0s + 64) * K + skc;
    const u16* Bg0 = Bt + (size_t)(col0 + r0s) * K + skc;
    const u16* Bg1 = Bt + (size_t)(col0 + r0s + 64) * K + skc;
    char* ldsA = (char*)&As[0][0][0];
    char* ldsB = (char*)&Bs[0][0][0];
    const int wb = wid << 10;

    f32x4 acc[2][4];
    #pragma unroll
    for (int i = 0; i < 2; ++i)
        #pragma unroll
        for (int q = 0; q < 4; ++q) acc[i][q] = (f32x4){0.f, 0.f, 0.f, 0.f};

    async16(Ag0, ldsA + wb);
    async16(Ag1, ldsA + 8192 + wb);
    async16(Bg0, ldsB + wb);
    async16(Bg1, ldsB + 8192 + wb);

    int cur = 0;
    for (int k0 = 0; k0 < K; k0 += 64) {
        if (k0 + 64 < K) {
            char* dA = ldsA + ((cur ^ 1) << 14);
            char* dB = ldsB + ((cur ^ 1) << 14);
            async16(Ag0 + k0 + 64, dA + wb);
            async16(Ag1 + k0 + 64, dA + 8192 + wb);
            async16(Bg0 + k0 + 64, dB + wb);
            async16(Bg1 + k0 + 64, dB + 8192 + wb);
            asm volatile("s_waitcnt vmcnt(4)" ::: "memory");
        } else {
            asm volatile("s_waitcnt vmcnt(0)" ::: "memory");
        }
        __builtin_amdgcn_s_barrier();
        __builtin_amdgcn_sched_barrier(0);
        char* rA = ldsA + (cur << 14);
        char* rB = ldsB + (cur << 14);
        const int mb = lane & 15, g = lane >> 4;
        #pragma unroll
        for (int kk = 0; kk < 2; ++kk) {
            bf16x8 a[2], b[4];
            #pragma unroll
            for (int i = 0; i < 2; ++i) {
                const int r = wr * 32 + i * 16 + mb;
                a[i] = *(const bf16x8*)(rA + r * 128 + ((((kk << 2) + g) ^ (r & 7)) << 4));
            }
            #pragma unroll
            for (int q = 0; q < 4; ++q) {
                const int r = wc * 64 + q * 16 + mb;
                b[q] = *(const bf16x8*)(rB + r * 128 + ((((kk << 2) + g) ^ (r & 7)) << 4));
            }
            #pragma unroll
            for (int i = 0; i < 2; ++i)
                #pragma unroll
                for (int q = 0; q < 4; ++q)
                    acc[i][q] = __builtin_amdgcn_mfma_f32_16x16x32_bf16(a[i], b[q], acc[i][q], 0, 0, 0);
        }
        __builtin_amdgcn_s_barrier();
        cur ^= 1;
    }

    #pragma unroll
    for (int i = 0; i < 2; ++i) {
        const int grow = row0 + wr * 32 + i * 16 + ((lane >> 4) << 2);
        #pragma unroll
        for (int q = 0; q < 4; ++q) {
            const int col = col0 + wc * 64 + q * 16 + (lane & 15);
            f32x4 v = acc[i][q];
            const float bv = bias[col];
            ushort4 pk;
            pk.x = f2bf(v[0] + bv); pk.y = f2bf(v[1] + bv);
            pk.z = f2bf(v[2] + bv); pk.w = f2bf(v[3] + bv);
            *(ushort4*)(Ct + ((size_t)((grow >> 11) * 256 + col)) * 2048 + (grow & 2047)) = pk;
        }
    }
}

// ---------------------------------------------------------------------------
// Adjacency GEMM: 512 threads / 8 waves, counted-vmcnt, supertile XCD decode.
// ---------------------------------------------------------------------------
__global__ __launch_bounds__(512) void bgemm_adj_k(
    const u16* __restrict__ A, const u16* __restrict__ Bt,
    u16* __restrict__ Cx, int K, long long bsB)
{
    __shared__ __align__(16) u16 As[2][128][64];
    __shared__ __align__(16) u16 Bs[2][128][64];

    const int tid = threadIdx.x;
    const int wid = tid >> 6, lane = tid & 63;
    const int wr = wid >> 1, wc = wid & 1;

    const int xcd = blockIdx.x & 7, loc = blockIdx.x >> 3;
    const int s = loc >> 4, w = loc & 15;
    const int sg = xcd * 16 + s;
    const int pzg = sg >> 2, bxg = sg & 3;
    const int bx = bxg * 4 + (w >> 2);
    const int pzidx = pzg * 4 + (w & 3);
    const int by = pzidx >> 6, bz = pzidx & 63;

    const int row0 = bx * 128, col0 = by * 128;
    const u16* Bp = Bt + (long long)bz * bsB;

    const int r0s = wid * 8 + (lane >> 3);
    const int c0 = lane & 7;
    const int sk0 = ((c0 ^ (r0s & 7)) << 3);
    const u16* Ag0 = A + (size_t)(row0 + r0s) * K + sk0;
    const u16* Ag1 = A + (size_t)(row0 + r0s + 64) * K + sk0;
    const u16* Bg0 = Bp + (size_t)(col0 + r0s) * K + sk0;
    const u16* Bg1 = Bp + (size_t)(col0 + r0s + 64) * K + sk0;
    char* ldsA = (char*)&As[0][0][0];
    char* ldsB = (char*)&Bs[0][0][0];
    const int wb = wid << 10;

    f32x4 acc[2][4];
    #pragma unroll
    for (int i = 0; i < 2; ++i)
        #pragma unroll
        for (int q = 0; q < 4; ++q) acc[i][q] = (f32x4){0.f, 0.f, 0.f, 0.f};

    async16(Ag0, ldsA + wb);
    async16(Ag1, ldsA + 8192 + wb);
    async16(Bg0, ldsB + wb);
    async16(Bg1, ldsB + 8192 + wb);

    int cur = 0;
    for (int k0 = 0; k0 < K; k0 += 64) {
        if (k0 + 64 < K) {
            char* dA = ldsA + ((cur ^ 1) << 14);
            char* dB = ldsB + ((cur ^ 1) << 14);
            async16(Ag0 + k0 + 64, dA + wb);
            async16(Ag1 + k0 + 64, dA + 8192 + wb);
            async16(Bg0 + k0 + 64, dB + wb);
            async16(Bg1 + k0 + 64, dB + 8192 + wb);
            asm volatile("s_waitcnt vmcnt(4)" ::: "memory");
        } else {
            asm volatile("s_waitcnt vmcnt(0)" ::: "memory");
        }
        __builtin_amdgcn_s_barrier();
        __builtin_amdgcn_sched_barrier(0);
        char* rA = ldsA + (cur << 14);
        char* rB = ldsB + (cur << 14);
        const int mb = lane & 15, g = lane >> 4;
        #pragma unroll
        for (int kk = 0; kk < 2; ++kk) {
            bf16x8 a[2], b[4];
            #pragma unroll
            for (int i = 0; i < 2; ++i) {
                const int r = wr * 32 + i * 16 + mb;
                a[i] = *(const bf16x8*)(rA + r * 128 + ((((kk << 2) + g) ^ (r & 7)) << 4));
            }
            #pragma unroll
            for (int q = 0; q < 4; ++q) {
                const int r = wc * 64 + q * 16 + mb;
                b[q] = *(const bf16x8*)(rB + r * 128 + ((((kk << 2) + g) ^ (r & 7)) << 4));
            }
            #pragma unroll
            for (int i = 0; i < 2; ++i)
                #pragma unroll
                for (int q = 0; q < 4; ++q)
                    acc[i][q] = __builtin_amdgcn_mfma_f32_16x16x32_bf16(a[i], b[q], acc[i][q], 0, 0, 0);
        }
        __builtin_amdgcn_s_barrier();
        cur ^= 1;
    }

    #pragma unroll
    for (int i = 0; i < 2; ++i) {
        const int grow = row0 + wr * 32 + i * 16 + ((lane >> 4) << 2);
        #pragma unroll
        for (int q = 0; q < 4; ++q) {
            const int col = col0 + wc * 64 + q * 16 + (lane & 15);
            f32x4 v = acc[i][q];
            #pragma unroll
            for (int r = 0; r < 4; ++r)
                Cx[((size_t)bz * 2048 + grow + r) * 256 + col] = f2bf(fmaxf(v[r], 0.f));
        }
    }
}

// is output position tt overwritten by a later pass?
__device__ __forceinline__ bool keep_out(int p, int tt) {
    if (p == 1) return ((tt & 1) == 0) && (tt % 3 != 2) && ((tt & 3) != 3);
    if (p == 2) return (tt % 3 != 2) && ((tt & 3) != 3);
    if (p == 3) return ((tt & 3) != 3);
    return true;
}

// decompose n -> (batch b, window w): shift path for pow2 nw (p=1,2,4)
__device__ __forceinline__ void bw_of(int n, int nw, int nwSh, unsigned& b, int& w) {
    if (nwSh >= 0) { b = (unsigned)n >> nwSh; w = n & (nw - 1); }
    else { b = (unsigned)n / (unsigned)nw; w = n - (int)b * nw; }
}

// ---------------------------------------------------------------------------
// LSTM step, M=128 tile, 512 threads / 8 waves, counted-vmcnt pipeline
// (4 loads/thread -> vmcnt(4)), 64KB LDS -> 2 blocks/CU = 16 waves/CU.
// ---------------------------------------------------------------------------
__global__ __launch_bounds__(512) void lstm_step_k(
    const u16* __restrict__ xsrc, const u16* __restrict__ hprev,
    u16* __restrict__ hnext, float* __restrict__ outF, float* __restrict__ cst,
    const u16* __restrict__ wih, const u16* __restrict__ whh,
    const float* __restrict__ biasp, int nw, int nwSh, int p, int j, int cpx, int writeH)
{
    __shared__ __align__(16) u16 As[2][128][64];
    __shared__ __align__(16) u16 Bs[2][128][64];

    const int tid = threadIdx.x;
    const int wid = tid >> 6, lane = tid & 63;
    const int wr = wid >> 1, wc = wid & 1;

    const int l = (blockIdx.x & 7) * cpx + (blockIdx.x >> 3);
    const int col0 = (l & 7) << 7;
    const int row0 = (l >> 3) << 7;
    const int first = (j == 0), last = (j == p - 1);

    const int r0s = wid * 8 + (lane >> 3);
    const int c0 = lane & 7;
    const int sk0 = ((c0 ^ (r0s & 7)) << 3);
    const int sk1 = ((c0 ^ ((r0s + 64) & 7)) << 3);

    const u16* axp[2];
    const u16* hpp[2];
    size_t wrow[2];
    {
        const int rr[2] = {r0s, r0s + 64};
        const int sk[2] = {sk0, sk1};
        #pragma unroll
        for (int s = 0; s < 2; ++s) {
            const int n = row0 + rr[s];
            unsigned b; int w;
            bw_of(n, nw, nwSh, b, w);
            axp[s] = xsrc + ((size_t)b * T2 + (size_t)w * p + j) * H2 + sk[s];
            hpp[s] = hprev ? hprev + (size_t)n * H2 + sk[s] : nullptr;
            wrow[s] = (size_t)(col0 + rr[s]) * H2 + sk[s];
        }
    }
    char* ldsA = (char*)&As[0][0][0];
    char* ldsB = (char*)&Bs[0][0][0];
    const int wb = wid << 10;

    f32x4 acc[2][4];
    #pragma unroll
    for (int i = 0; i < 2; ++i)
        #pragma unroll
        for (int q = 0; q < 4; ++q) acc[i][q] = (f32x4){0.f, 0.f, 0.f, 0.f};

    const int KT = first ? 256 : 512;

    #pragma unroll
    for (int s = 0; s < 2; ++s) {
        async16(axp[s], ldsA + s * 8192 + wb);
        async16(wih + wrow[s], ldsB + s * 8192 + wb);
    }

    int cur = 0;
    for (int k0 = 0; k0 < KT; k0 += 64) {
        const int kn = k0 + 64;
        if (kn < KT) {
            char* dA = ldsA + ((cur ^ 1) << 14);
            char* dB = ldsB + ((cur ^ 1) << 14);
            if (kn < 256) {
                #pragma unroll
                for (int s = 0; s < 2; ++s) {
                    async16(axp[s] + kn, dA + s * 8192 + wb);
                    async16(wih + wrow[s] + kn, dB + s * 8192 + wb);
                }
            } else {
                const int kk2 = kn - 256;
                #pragma unroll
                for (int s = 0; s < 2; ++s) {
                    async16(hpp[s] + kk2, dA + s * 8192 + wb);
                    async16(whh + wrow[s] + kk2, dB + s * 8192 + wb);
                }
            }
            asm volatile("s_waitcnt vmcnt(4)" ::: "memory");
        } else {
            asm volatile("s_waitcnt vmcnt(0)" ::: "memory");
        }
        __builtin_amdgcn_s_barrier();
        __builtin_amdgcn_sched_barrier(0);
        char* rA = ldsA + (cur << 14);
        char* rB = ldsB + (cur << 14);
        const int mb = lane & 15, g = lane >> 4;
        #pragma unroll
        for (int kk = 0; kk < 2; ++kk) {
            bf16x8 a[2], b[4];
            #pragma unroll
            for (int i = 0; i < 2; ++i) {
                const int r = wr * 32 + i * 16 + mb;
                a[i] = *(const bf16x8*)(rA + r * 128 + ((((kk << 2) + g) ^ (r & 7)) << 4));
            }
            #pragma unroll
            for (int q = 0; q < 4; ++q) {
                const int r = wc * 64 + q * 16 + mb;
                b[q] = *(const bf16x8*)(rB + r * 128 + ((((kk << 2) + g) ^ (r & 7)) << 4));
            }
            #pragma unroll
            for (int i = 0; i < 2; ++i)
                #pragma unroll
                for (int q = 0; q < 4; ++q)
                    acc[i][q] = __builtin_amdgcn_mfma_f32_16x16x32_bf16(a[i], b[q], acc[i][q], 0, 0, 0);
        }
        __builtin_amdgcn_s_barrier();
        cur ^= 1;
    }

    const int u = lane & 15;
    const int colb = col0 + wc * 64;
    const int hu = (colb >> 2) + u;
    float bq[4];
    #pragma unroll
    for (int q = 0; q < 4; ++q) bq[q] = biasp[colb + q * 16 + u];

    #pragma unroll
    for (int i = 0; i < 2; ++i) {
        const int rbase = row0 + wr * 32 + i * 16 + ((lane >> 4) << 2);
        #pragma unroll
        for (int r = 0; r < 4; ++r) {
            const int n = rbase + r;
            const float gi = acc[i][0][r] + bq[0];
            const float gf = acc[i][1][r] + bq[1];
            const float gg = acc[i][2][r] + bq[2];
            const float go = acc[i][3][r] + bq[3];
            const float si = sig_f(gi), sf = sig_f(gf), so = sig_f(go);
            const float tg = tanh_f(gg);
            const float cp = first ? 0.f : cst[(size_t)n * H2 + hu];
            const float cn = sf * cp + si * tg;
            const float hv = so * tanh_f(cn);
            if (writeH) hnext[(size_t)n * H2 + hu] = f2bf(hv);
            if (last) {
                unsigned b; int w;
                bw_of(n, nw, nwSh, b, w);
                const int tt = w * p + (p - 1);
                if (keep_out(p, tt))
                    outF[((size_t)b * T2 + tt) * H2 + hu] = hv;
            } else {
                cst[(size_t)n * H2 + hu] = cn;
            }
        }
    }
}

// update mirror at window-end positions from deferred hnext (bf16 copy)
__global__ __launch_bounds__(256) void scatter_ax_k(
    const u16* __restrict__ hs, u16* __restrict__ mir, int nw, int nwSh, int p, int Nrows)
{
    const int idx = blockIdx.x * 256 + threadIdx.x;
    if (idx >= Nrows * 32) return;
    const int n = idx >> 5, c8 = (idx & 31) << 3;
    unsigned b; int w;
    bw_of(n, nw, nwSh, b, w);
    *(uint4*)(mir + ((size_t)b * T2 + (size_t)w * p + (p - 1)) * H2 + c8) =
        *(const uint4*)(hs + (size_t)n * H2 + c8);
}

// Wg transpose+cast: out[n][k] = bf16(in[k][n]), 256x256
__global__ __launch_bounds__(256) void convT_k(const float* __restrict__ in, u16* __restrict__ out)
{
    const int idx = blockIdx.x * 256 + threadIdx.x;
    const int r = idx >> 8, c = idx & 255;
    out[(size_t)c * 256 + r] = f2bf(in[idx]);
}

// LSTM weight gate-major permute: wP[pass][n'][k], n' = (h>>4)*64+g*16+(h&15)
__global__ __launch_bounds__(256) void convW_k(
    const float* __restrict__ Wih, const float* __restrict__ Whh,
    u16* __restrict__ wih_p, u16* __restrict__ whh_p)
{
    const int idx = blockIdx.x * 256 + threadIdx.x;
    const int pp = idx >> 18;
    const int np = (idx >> 8) & 1023;
    const int k = idx & 255;
    const int group = np >> 6, g = (np >> 4) & 3, uu = np & 15;
    const int hh = group * 16 + uu;
    const size_t src = (size_t)pp * 262144 + (size_t)(g * 256 + hh) * 256 + k;
    wih_p[idx] = f2bf(Wih[src]);
    whh_p[idx] = f2bf(Whh[src]);
}

__global__ __launch_bounds__(256) void convB_k(
    const float* __restrict__ bih, const float* __restrict__ bhh, float* __restrict__ bp)
{
    const int idx = blockIdx.x * 256 + threadIdx.x;
    const int pp = idx >> 10, np = idx & 1023;
    const int group = np >> 6, g = (np >> 4) & 3, uu = np & 15;
    const int hh = group * 16 + uu;
    bp[idx] = bih[pp * 1024 + g * 256 + hh] + bhh[pp * 1024 + g * 256 + hh];
}

// ---------------------------------------------------------------------------
extern "C" void kernel_launch(void* const* d_in, const int* in_sizes, int n_in,
                              void* d_out, int out_size, void* d_ws, size_t ws_size,
                              hipStream_t stream)
{
    const float* x   = (const float*)d_in[0];
    const float* adj = (const float*)d_in[1];
    const float* Wg0 = (const float*)d_in[2];
    const float* bg0 = (const float*)d_in[3];
    const float* Wg1 = (const float*)d_in[4];
    const float* bg1 = (const float*)d_in[5];
    const float* Wih = (const float*)d_in[6];
    const float* Whh = (const float*)d_in[7];
    const float* bih = (const float*)d_in[8];
    const float* bhh = (const float*)d_in[9];
    float* out = (float*)d_out;

    char* ws = (char*)d_ws;
    u16*   Ax   = (u16*)ws;                         // 67MB: GCN h mirror; p>=2 ping-pong
    u16*   hs0  = Ax;
    u16*   hs1  = (u16*)(ws + 33554432);
    u16*   hsB  = (u16*)(ws + 67108864);            // 67MB: St (GCN) / t-indexed mirror (LSTM)
    float* cst  = (float*)(ws + 134217728);         // 67MB: f32 cell state
    char*  wreg = ws + 201326592;                   // 8MB region
    u16*   adjbf = (u16*)wreg;                      //   GCN phase
    u16*   wihP  = (u16*)wreg;                      //   LSTM phase (adjbf dead)
    u16*   whhP  = (u16*)(wreg + 2097152);
    float* bp    = (float*)(wreg + 4194304);
    u16*   wg0t  = (u16*)(ws + 209715200);
    u16*   wg1t  = (u16*)(ws + 209846272);
    u16*   St    = hsB;

    // ---- casts / weight prep ----
    cast_bf16_k<<<4096, 256, 0, stream>>>(adj, adjbf, 1048576);
    convT_k<<<256, 256, 0, stream>>>(Wg0, wg0t);
    convT_k<<<256, 256, 0, stream>>>(Wg1, wg1t);

    // ---- GCN ----
    bgemm_sup_f32a_k<<<2048, 512, 0, stream>>>(x, wg0t, bg0, St);
    bgemm_adj_k<<<2048, 512, 0, stream>>>(adjbf, St, Ax, 2048, (long long)256 * 2048);
    bgemm_sup_k<<<2048, 512, 0, stream>>>(Ax, wg1t, bg1, St);
    bgemm_adj_k<<<2048, 512, 0, stream>>>(adjbf, St, Ax, 2048, (long long)256 * 2048);

    // ---- LSTM weights (adjbf dead) ----
    convW_k<<<4096, 256, 0, stream>>>(Wih, Whh, wihP, whhP);
    convB_k<<<16, 256, 0, stream>>>(bih, bhh, bp);

    // ---- skip-LSTM passes ----
    for (int p = 1; p <= MAXP; ++p) {
        const int nw = T2 / p;
        const int nwSh = (p == 1) ? 11 : (p == 2) ? 10 : (p == 4) ? 9 : -1;
        const int Nrows = 64 * nw;                  // 131072 / 65536 / 43648 / 32768
        const int cpx = Nrows / 128;                // 1024 / 512 / 341 / 256
        const u16* wihp = wihP + (size_t)(p - 1) * 262144;
        const u16* whhp = whhP + (size_t)(p - 1) * 262144;
        const float* bpp = bp + (size_t)(p - 1) * 1024;
        const u16* xs = (p == 1) ? Ax : hsB;
        for (int j = 0; j < p; ++j) {
            u16* hn = (p == 1) ? hsB : ((j & 1) ? hs1 : hs0);
            const u16* hpv = (j == 0) ? nullptr : ((j & 1) ? hs0 : hs1);
            const int writeH = !(p == MAXP && j == p - 1);
            lstm_step_k<<<cpx * 8, 512, 0, stream>>>(
                xs, hpv, hn, out, cst, wihp, whhp, bpp, nw, nwSh, p, j, cpx, writeH);
        }
        if (p >= 2 && p != MAXP) {
            const u16* hlast = ((p - 1) & 1) ? hs1 : hs0;
            scatter_ax_k<<<(Nrows * 32 + 255) / 256, 256, 0, stream>>>(hlast, hsB, nw, nwSh, p, Nrows);
        }
    }
}